// Round 4
// baseline (261.990 us; speedup 1.0000x reference)
//
#include <hip/hip_runtime.h>
#include <hip/hip_bf16.h>

// B=4, N=2048, C=768, H=16, D=48. FP32 in/out.
// Pipeline: cvt(x,W->bf16, Vf-pad) -> gemm_qkv (fused, writes Q/K/V directly in
//           MFMA-fragment layouts) -> attn (LDS-staged K/V, counted-vmcnt
//           depth-2 pipeline, all-register P via cvt_pk+permlane) -> gemm_out.
#define B_ 4
#define N_ 2048
#define C_ 768
#define H_ 16
#define D_ 48
#define SCALE_ 0.14433756729740643f
#define LOG2E_ 1.44269504088896f

using bf16 = __hip_bfloat16;
using bf16x8 = __attribute__((ext_vector_type(8))) short;
using f32x4  = __attribute__((ext_vector_type(4))) float;
using f32x16 = __attribute__((ext_vector_type(16))) float;
using u32x2  = __attribute__((ext_vector_type(2))) unsigned int;
using u32x4  = __attribute__((ext_vector_type(4))) unsigned int;

__device__ __forceinline__ unsigned short f2b(float f) {
  bf16 h = __float2bfloat16(f);
  return *reinterpret_cast<unsigned short*>(&h);
}
__device__ __forceinline__ unsigned int pack2(float lo, float hi) {
  return (unsigned int)f2b(lo) | ((unsigned int)f2b(hi) << 16);
}
// packed f32->bf16 (RNE), single instruction
__device__ __forceinline__ unsigned int pk2(float lo, float hi) {
  unsigned int r;
  asm("v_cvt_pk_bf16_f32 %0, %1, %2" : "=v"(r) : "v"(lo), "v"(hi));
  return r;
}
__device__ __forceinline__ uint4 ld8f_cvt(const float* p) {
  float4 a = *reinterpret_cast<const float4*>(p);
  float4 b = *reinterpret_cast<const float4*>(p + 4);
  uint4 u;
  u.x = pack2(a.x, a.y); u.y = pack2(a.z, a.w);
  u.z = pack2(b.x, b.y); u.w = pack2(b.z, b.w);
  return u;
}
// async global->LDS, 16B per lane; LDS dest = wave-uniform base + lane*16B
__device__ __forceinline__ void gload_lds16(const bf16* g, bf16* l) {
  __builtin_amdgcn_global_load_lds(
      (const __attribute__((address_space(1))) unsigned int*)g,
      (__attribute__((address_space(3))) unsigned int*)l, 16, 0, 0);
}

// ---- Kernel 0: fp32 -> bf16 conversions + static Vf pad fill.
// Fragment-layout pad of Vf (d-rows 48..63): row 48 = 1.0 (fused L row-sum),
// rows 49..63 = 0. Address: bh*131072 + n4*1024 + 512 + hi*256 + m5*8 (+e).
__global__ __launch_bounds__(256) void cvt_bf16(
    const float* __restrict__ x,  const float* __restrict__ wq,
    const float* __restrict__ wk, const float* __restrict__ wv,
    const float* __restrict__ wo,
    bf16* __restrict__ xb, bf16* __restrict__ wqkvb, bf16* __restrict__ wob,
    bf16* __restrict__ vfp)
{
  const int job = blockIdx.y;
  if (job == 5) {
    for (int u = blockIdx.x * 256 + threadIdx.x; u < 64 * 128 * 32;
         u += gridDim.x * 256) {
      const int m5i = u & 15, hb = (u >> 4) & 1, n4 = (u >> 5) & 127,
                bh = u >> 12;
      const short fill = (m5i == 0) ? (short)0x3F80 : (short)0;
      const bf16x8 o = {fill, fill, fill, fill, fill, fill, fill, fill};
      *(bf16x8*)(vfp + (size_t)bh * 131072 + n4 * 1024 + 512 + hb * 256 +
                 (16 + m5i) * 8) = o;
    }
    return;
  }
  const float* src; bf16* dst; int n;
  if (job == 0)      { src = x;  dst = xb;              n = B_ * N_ * C_; }
  else if (job == 1) { src = wq; dst = wqkvb;           n = C_ * C_; }
  else if (job == 2) { src = wk; dst = wqkvb + C_ * C_; n = C_ * C_; }
  else if (job == 3) { src = wv; dst = wqkvb + 2 * C_ * C_; n = C_ * C_; }
  else               { src = wo; dst = wob;             n = C_ * C_; }
  const int stride = gridDim.x * 256 * 8;
  for (int i = (blockIdx.x * 256 + threadIdx.x) * 8; i < n; i += stride)
    *(uint4*)(dst + i) = ld8f_cvt(src + i);
}

// ---- Kernel 1: fused QKV GEMM, m97-style. A=xb[8192x768], B=Wqkv[2304x768].
// Epilogue writes DIRECTLY in MFMA-fragment layouts (no reshape kernel):
//  Q/K(n,d): slab + (n>>5)*1536 + (d>>4)*512 + ((d>>3)&1)*256 + (n&31)*8 + (d&7)
//  Vf (n,d): slabV + (n>>4)*1024 + (d>>5)*512 + ((n>>3)&1)*256 + (d&31)*8 + (n&7)
__global__ __launch_bounds__(256) void gemm_qkv(
    const bf16* __restrict__ A, const bf16* __restrict__ Bw,
    const float* __restrict__ bq, const float* __restrict__ bk,
    const float* __restrict__ bv,
    bf16* __restrict__ Q, bf16* __restrict__ K, bf16* __restrict__ Vf)
{
  __shared__ __align__(16) bf16 As[128 * 64];
  __shared__ __align__(16) bf16 Bs[128 * 64];

  const int tid  = threadIdx.x;
  const int lane = tid & 63, wid = tid >> 6;
  const int wm = (wid >> 1) * 64, wn = (wid & 1) * 64;
  const int row0 = blockIdx.y * 128, col0 = blockIdx.x * 128;
  const int mb = lane & 15, g4 = lane >> 4;
  const int srow = lane >> 3;                    // staging row-in-8
  const int schunk = (lane & 7) ^ (srow & 7);    // swizzled glb k-chunk

  f32x4 acc[4][4];
#pragma unroll
  for (int i = 0; i < 4; ++i)
#pragma unroll
    for (int j = 0; j < 4; ++j) acc[i][j] = (f32x4){0.f, 0.f, 0.f, 0.f};

  for (int k0 = 0; k0 < C_; k0 += 64) {
#pragma unroll
    for (int t = 0; t < 4; ++t) {
      const int rt = wid * 32 + t * 8;
      gload_lds16(A  + (size_t)(row0 + rt + srow) * C_ + k0 + schunk * 8,
                  As + rt * 64);
      gload_lds16(Bw + (size_t)(col0 + rt + srow) * C_ + k0 + schunk * 8,
                  Bs + rt * 64);
    }
    __syncthreads();
#pragma unroll
    for (int ks = 0; ks < 2; ++ks) {
      const int kchunk = ks * 4 + g4;
      bf16x8 af[4], bfr[4];
#pragma unroll
      for (int i = 0; i < 4; ++i) {
        const int row = wm + i * 16 + mb;
        af[i] = *(const bf16x8*)(As + row * 64 + (kchunk ^ (row & 7)) * 8);
      }
#pragma unroll
      for (int j = 0; j < 4; ++j) {
        const int col = wn + j * 16 + mb;
        bfr[j] = *(const bf16x8*)(Bs + col * 64 + (kchunk ^ (col & 7)) * 8);
      }
#pragma unroll
      for (int i = 0; i < 4; ++i)
#pragma unroll
        for (int j = 0; j < 4; ++j)
          acc[i][j] = __builtin_amdgcn_mfma_f32_16x16x32_bf16(af[i], bfr[j], acc[i][j], 0, 0, 0);
    }
    __syncthreads();
  }

  const int z = blockIdx.x / 6;                  // 768/128=6 blocks per proj
  const int b_ = row0 >> 11;
  const int nb = (row0 & (N_ - 1)) + wm;         // local-n base of this wave
  if (z < 2) {                                   // ---- Q or K
    const float* bias = (z == 0) ? bq : bk;
    bf16* dst = (z == 0) ? Q : K;
    const float sc = (z == 0) ? (SCALE_ * LOG2E_) : 1.0f;
#pragma unroll
    for (int j = 0; j < 4; ++j) {
      const int oo = col0 - z * 768 + wn + j * 16 + mb;
      const int h = oo / D_, d = oo % D_;
      const float bb = bias[oo];
      bf16* slabp = dst + (size_t)(b_ * H_ + h) * (N_ * D_);
      const int dpart = (d >> 4) * 512 + ((d >> 3) & 1) * 256 + (d & 7);
#pragma unroll
      for (int i = 0; i < 4; ++i) {
        const int base2 = ((nb >> 5) + (i >> 1)) * 1536 + dpart;
        const int mlo = (i & 1) * 16 + g4 * 4;
#pragma unroll
        for (int reg = 0; reg < 4; ++reg)
          slabp[base2 + (mlo + reg) * 8] =
              __float2bfloat16((acc[i][j][reg] + bb) * sc);
      }
    }
  } else {                                       // ---- V -> Vf (8B stores)
#pragma unroll
    for (int j = 0; j < 4; ++j) {
      const int oo = col0 - 2 * 768 + wn + j * 16 + mb;
      const int h = oo / D_, d = oo % D_;
      const float bb = bv[oo];
      bf16* slabp = Vf + (size_t)(b_ * H_ + h) * (N_ * 64);
      const int dpart = (d >> 5) * 512 + ((g4 >> 1) * 32 + (d & 31)) * 8 +
                        (g4 & 1) * 4;
#pragma unroll
      for (int i = 0; i < 4; ++i) {
        u32x2 wv;
        wv.x = pk2(acc[i][j][0] + bb, acc[i][j][1] + bb);
        wv.y = pk2(acc[i][j][2] + bb, acc[i][j][3] + bb);
        *(u32x2*)(slabp + ((nb >> 4) + i) * 1024 + dpart) = wv;
      }
    }
  }
}

// ---- Kernel 2: LDS-staged register flash attention, counted-vmcnt pipeline.
// 3 LDS buffers, depth-2 prefetch. Waves 0-1 stage 7 chunks each per 64-key
// tile; per-iter: s_barrier -> stage(t+2) -> compute(t) -> s_waitcnt vmcnt(7)
// (tile t+1 landed; t+2 stays IN FLIGHT across the barrier — no vmcnt(0) drain).
__global__ __launch_bounds__(256, 4) void attn_mfma(
    const bf16* __restrict__ Qf, const bf16* __restrict__ Kf,
    const bf16* __restrict__ Vf, const float* __restrict__ x,
    bf16* __restrict__ Yb)
{
  __shared__ __align__(16) bf16 Ls[3 * 7168];    // 3 bufs x (6KB K + 8KB V)

  const int tid  = threadIdx.x;
  const int lane = tid & 63, wid = tid >> 6;
  const int m5 = lane & 31, hi = lane >> 5;
  const int bh = blockIdx.x;
  const int b_ = bh >> 4, h = bh & 15;
  const int q0 = blockIdx.y * 128 + wid * 32;
  const size_t slab  = (size_t)bh * (N_ * D_);
  const size_t slabV = (size_t)bh * (N_ * 64);

  // Q fragments (32 q rows x 48 d), live whole kernel
  bf16x8 qf[3];
  const int kgq = q0 >> 5;
#pragma unroll
  for (int kc = 0; kc < 3; ++kc)
    qf[kc] = *(const bf16x8*)(Qf + slab + (size_t)(((kgq * 3 + kc) * 64) + lane) * 8);

  f32x16 zf;
#pragma unroll
  for (int r = 0; r < 16; ++r) zf[r] = 0.f;

  f32x16 Oacc[2];
#pragma unroll
  for (int dt = 0; dt < 2; ++dt)
#pragma unroll
    for (int r = 0; r < 16; ++r) Oacc[dt][r] = 0.f;

  // stage tile t (64 keys): chunks 0-5 = K (6KB), 6-13 = V (8KB).
  // Only waves 0,1 stage (7 chunks each -> uniform vmcnt counts).
  const bf16* kb = Kf + slab  + (size_t)lane * 8;
  const bf16* vb = Vf + slabV + (size_t)lane * 8;
  auto stage = [&](int t, int buf) {
    if (wid < 2) {
      bf16* dstb = Ls + buf * 7168;
      const bf16* kt = kb + (size_t)t * 3072;
      const bf16* vt = vb + (size_t)t * 4096;
#pragma unroll
      for (int cc = 0; cc < 7; ++cc) {
        const int c = wid * 7 + cc;
        if (c < 6) gload_lds16(kt + c * 512, dstb + c * 512);
        else       gload_lds16(vt + (c - 6) * 512, dstb + c * 512);
      }
    }
  };

  // compute one 32-key sub-tile from LDS buffer buf
  auto sub = [&](int buf, int s) {
    const bf16* Lb = Ls + buf * 7168 + (size_t)lane * 8;
    bf16x8 kf[3], vA[2][2];
#pragma unroll
    for (int kc = 0; kc < 3; ++kc)
      kf[kc] = *(const bf16x8*)(Lb + (s * 3 + kc) * 512);
#pragma unroll
    for (int ks = 0; ks < 2; ++ks)
#pragma unroll
      for (int dt = 0; dt < 2; ++dt)
        vA[ks][dt] = *(const bf16x8*)(Lb + (6 + s * 4 + ks * 2 + dt) * 512);
    f32x16 S;
    __builtin_amdgcn_s_setprio(1);
    S = __builtin_amdgcn_mfma_f32_32x32x16_bf16(kf[0], qf[0], zf, 0, 0, 0);
    S = __builtin_amdgcn_mfma_f32_32x32x16_bf16(kf[1], qf[1], S, 0, 0, 0);
    S = __builtin_amdgcn_mfma_f32_32x32x16_bf16(kf[2], qf[2], S, 0, 0, 0);
    __builtin_amdgcn_s_setprio(0);
#pragma unroll
    for (int r = 0; r < 16; ++r)
      S[r] = __builtin_amdgcn_exp2f(S[r]);
    // S reg 4*qq+rr = P[q=lane&31][k32 = rr + 8*qq + 4*hi]
#pragma unroll
    for (int ks = 0; ks < 2; ++ks) {
      const int qa = ks * 2;
      const unsigned A0 = pk2(S[4 * qa + 0], S[4 * qa + 1]);
      const unsigned A1 = pk2(S[4 * qa + 2], S[4 * qa + 3]);
      const unsigned B0 = pk2(S[4 * qa + 4], S[4 * qa + 5]);
      const unsigned B1 = pk2(S[4 * qa + 6], S[4 * qa + 7]);
      const u32x2 r02 = __builtin_amdgcn_permlane32_swap(A0, B0, false, false);
      const u32x2 r13 = __builtin_amdgcn_permlane32_swap(A1, B1, false, false);
      u32x4 pw;
      pw.x = r02.x; pw.y = r13.x; pw.z = r02.y; pw.w = r13.y;
      const bf16x8 pb = (bf16x8)pw;
      __builtin_amdgcn_s_setprio(1);
      Oacc[0] = __builtin_amdgcn_mfma_f32_32x32x16_bf16(vA[ks][0], pb, Oacc[0], 0, 0, 0);
      Oacc[1] = __builtin_amdgcn_mfma_f32_32x32x16_bf16(vA[ks][1], pb, Oacc[1], 0, 0, 0);
      __builtin_amdgcn_s_setprio(0);
    }
  };

  stage(0, 0);
  stage(1, 1);
  // loaders: qf(3) + 14 staging loads outstanding; wait until <=7 ->
  // qf + tile0 landed, tile1 still in flight. Non-loaders: no-op.
  asm volatile("s_waitcnt vmcnt(7)" ::: "memory");
#pragma unroll 1
  for (int t = 0; t < 32; ++t) {
    __builtin_amdgcn_s_barrier();      // publishes tile t (loaders waited pre-barrier)
    if (t + 2 < 32) stage(t + 2, (t + 2) % 3);  // overwrites buf of t-1 (reads done)
    sub(t % 3, 0);
    sub(t % 3, 1);
    if (t < 30)       asm volatile("s_waitcnt vmcnt(7)" ::: "memory");
    else if (t == 30) asm volatile("s_waitcnt vmcnt(0)" ::: "memory");
  }

  // L[q] lives in Oacc[1] row 16 = reg 8 of hi=0 lanes; broadcast to hi=1.
  const float lf = Oacc[1][8];
  const unsigned lu = __builtin_bit_cast(unsigned, lf);
  const u32x2 lsw = __builtin_amdgcn_permlane32_swap(lu, lu, false, false);
  const float Lv = __builtin_bit_cast(float, lsw.x);
  const float inv = 1.f / Lv;

  const int n = q0 + m5;
  const size_t rowoff = ((size_t)(b_ * N_ + n)) * C_ + h * D_;
#pragma unroll
  for (int qq = 0; qq < 4; ++qq) {
    const size_t off = rowoff + 8 * qq + 4 * hi;      // d = 8qq+4hi .. +3
    const float4 xr = *(const float4*)(x + off);
    u32x2 wv;
    wv.x = pk2(Oacc[0][4 * qq + 0] * inv + xr.x, Oacc[0][4 * qq + 1] * inv + xr.y);
    wv.y = pk2(Oacc[0][4 * qq + 2] * inv + xr.z, Oacc[0][4 * qq + 3] * inv + xr.w);
    *(u32x2*)(Yb + off) = wv;
  }
#pragma unroll
  for (int qq = 0; qq < 2; ++qq) {
    const size_t off = rowoff + 32 + 8 * qq + 4 * hi; // d = 32+8qq+4hi .. +3
    const float4 xr = *(const float4*)(x + off);
    u32x2 wv;
    wv.x = pk2(Oacc[1][4 * qq + 0] * inv + xr.x, Oacc[1][4 * qq + 1] * inv + xr.y);
    wv.y = pk2(Oacc[1][4 * qq + 2] * inv + xr.z, Oacc[1][4 * qq + 3] * inv + xr.w);
    *(u32x2*)(Yb + off) = wv;
  }
}

// ---- Kernel 3: O projection + residuals, m97-style staging.
// out[r][o] = acc + bo[o] + float(Yb[r][o]) + x[r][o]
__global__ __launch_bounds__(256) void gemm_out(
    const bf16* __restrict__ Yb, const bf16* __restrict__ Bw,
    const float* __restrict__ bo, const float* __restrict__ x,
    float* __restrict__ out)
{
  __shared__ __align__(16) bf16 As[128 * 64];
  __shared__ __align__(16) bf16 Bs[128 * 64];

  const int tid  = threadIdx.x;
  const int lane = tid & 63, wid = tid >> 6;
  const int wm = (wid >> 1) * 64, wn = (wid & 1) * 64;
  const int row0 = blockIdx.y * 128, col0 = blockIdx.x * 128;
  const int mb = lane & 15, g4 = lane >> 4;
  const int srow = lane >> 3;
  const int schunk = (lane & 7) ^ (srow & 7);

  f32x4 acc[4][4];
#pragma unroll
  for (int i = 0; i < 4; ++i)
#pragma unroll
    for (int j = 0; j < 4; ++j) acc[i][j] = (f32x4){0.f, 0.f, 0.f, 0.f};

  for (int k0 = 0; k0 < C_; k0 += 64) {
#pragma unroll
    for (int t = 0; t < 4; ++t) {
      const int rt = wid * 32 + t * 8;
      gload_lds16(Yb + (size_t)(row0 + rt + srow) * C_ + k0 + schunk * 8,
                  As + rt * 64);
      gload_lds16(Bw + (size_t)(col0 + rt + srow) * C_ + k0 + schunk * 8,
                  Bs + rt * 64);
    }
    __syncthreads();
#pragma unroll
    for (int ks = 0; ks < 2; ++ks) {
      const int kchunk = ks * 4 + g4;
      bf16x8 af[4], bfr[4];
#pragma unroll
      for (int i = 0; i < 4; ++i) {
        const int row = wm + i * 16 + mb;
        af[i] = *(const bf16x8*)(As + row * 64 + (kchunk ^ (row & 7)) * 8);
      }
#pragma unroll
      for (int j = 0; j < 4; ++j) {
        const int col = wn + j * 16 + mb;
        bfr[j] = *(const bf16x8*)(Bs + col * 64 + (kchunk ^ (col & 7)) * 8);
      }
#pragma unroll
      for (int i = 0; i < 4; ++i)
#pragma unroll
        for (int j = 0; j < 4; ++j)
          acc[i][j] = __builtin_amdgcn_mfma_f32_16x16x32_bf16(af[i], bfr[j], acc[i][j], 0, 0, 0);
    }
    __syncthreads();
  }

  const int crow = g4 * 4;
#pragma unroll
  for (int j = 0; j < 4; ++j) {
    const int o = col0 + wn + j * 16 + mb;
    const float bb = bo[o];
#pragma unroll
    for (int i = 0; i < 4; ++i) {
#pragma unroll
      for (int reg = 0; reg < 4; ++reg) {
        const int r = row0 + wm + i * 16 + crow + reg;
        const size_t off = (size_t)r * C_ + o;
        out[off] = acc[i][j][reg] + bb + __bfloat162float(Yb[off]) + x[off];
      }
    }
  }
}

extern "C" void kernel_launch(void* const* d_in, const int* in_sizes, int n_in,
                              void* d_out, int out_size, void* d_ws, size_t ws_size,
                              hipStream_t stream)
{
  const float* x  = (const float*)d_in[0];
  const float* wq = (const float*)d_in[1];
  const float* bq = (const float*)d_in[2];
  const float* wk = (const float*)d_in[3];
  const float* bk = (const float*)d_in[4];
  const float* wv = (const float*)d_in[5];
  const float* bv = (const float*)d_in[6];
  const float* wo = (const float*)d_in[7];
  const float* bo = (const float*)d_in[8];
  float* out = (float*)d_out;

  const size_t nEl  = (size_t)B_ * N_ * C_;      // 6,291,456
  const size_t wEl  = (size_t)C_ * C_;           // 589,824
  const size_t vfEl = (size_t)B_ * H_ * N_ * 64; // 8,388,608 (padded V frags)
  bf16* Q     = (bf16*)d_ws;                     // fragment layouts
  bf16* K     = Q + nEl;
  bf16* Vf    = K + nEl;                         // padded V A-fragment layout
  bf16* Yb    = Vf + vfEl;                       // y = attn+x, bf16
  bf16* xb    = Yb + nEl;                        // [8192][768] bf16
  bf16* wqkvb = xb + nEl;                        // [2304][768] bf16 stacked
  bf16* wob   = wqkvb + 3 * wEl;                 // [768][768] bf16

  dim3 gcvt(768, 6);                             // job 5 = Vf pad fill
  cvt_bf16<<<gcvt, dim3(256), 0, stream>>>(x, wq, wk, wv, wo, xb, wqkvb, wob, Vf);

  dim3 gqkv(18, 64);                             // 2304/128 x 8192/128
  gemm_qkv<<<gqkv, dim3(256), 0, stream>>>(xb, wqkvb, bq, bk, bv, Q, K, Vf);

  dim3 gattn(B_ * H_, N_ / 128);                 // (64, 16)
  attn_mfma<<<gattn, dim3(256), 0, stream>>>(Q, K, Vf, x, Yb);

  dim3 gout(6, 64);                              // 768/128 x 8192/128
  gemm_out<<<gout, dim3(256), 0, stream>>>(Yb, wob, bo, x, out);
}

// Round 5
// 250.617 us; speedup vs baseline: 1.0454x; 1.0454x over previous
//
#include <hip/hip_runtime.h>
#include <hip/hip_bf16.h>

// B=4, N=2048, C=768, H=16, D=48. FP32 in/out.
// Pipeline: cvt(x,W->bf16, Vf-pad) -> gemm_qkv (fused, writes Q/K/V directly in
//           MFMA-fragment layouts) -> attn (LDS-staged K/V shared by 4 waves,
//           double-buffered global_load_lds prefetch; all-register P via
//           cvt_pk+permlane) -> gemm_out.
#define B_ 4
#define N_ 2048
#define C_ 768
#define H_ 16
#define D_ 48
#define SCALE_ 0.14433756729740643f
#define LOG2E_ 1.44269504088896f

using bf16 = __hip_bfloat16;
using bf16x8 = __attribute__((ext_vector_type(8))) short;
using f32x4  = __attribute__((ext_vector_type(4))) float;
using f32x16 = __attribute__((ext_vector_type(16))) float;
using u32x2  = __attribute__((ext_vector_type(2))) unsigned int;
using u32x4  = __attribute__((ext_vector_type(4))) unsigned int;

__device__ __forceinline__ unsigned short f2b(float f) {
  bf16 h = __float2bfloat16(f);
  return *reinterpret_cast<unsigned short*>(&h);
}
__device__ __forceinline__ unsigned int pack2(float lo, float hi) {
  return (unsigned int)f2b(lo) | ((unsigned int)f2b(hi) << 16);
}
// packed f32->bf16 (RNE), single instruction
__device__ __forceinline__ unsigned int pk2(float lo, float hi) {
  unsigned int r;
  asm("v_cvt_pk_bf16_f32 %0, %1, %2" : "=v"(r) : "v"(lo), "v"(hi));
  return r;
}
__device__ __forceinline__ uint4 ld8f_cvt(const float* p) {
  float4 a = *reinterpret_cast<const float4*>(p);
  float4 b = *reinterpret_cast<const float4*>(p + 4);
  uint4 u;
  u.x = pack2(a.x, a.y); u.y = pack2(a.z, a.w);
  u.z = pack2(b.x, b.y); u.w = pack2(b.z, b.w);
  return u;
}
// async global->LDS, 16B per lane; LDS dest = wave-uniform base + lane*16B
__device__ __forceinline__ void gload_lds16(const bf16* g, bf16* l) {
  __builtin_amdgcn_global_load_lds(
      (const __attribute__((address_space(1))) unsigned int*)g,
      (__attribute__((address_space(3))) unsigned int*)l, 16, 0, 0);
}

// ---- Kernel 0: fp32 -> bf16 conversions + static Vf pad fill.
// Fragment-layout pad of Vf (d-rows 48..63): row 48 = 1.0 (fused L row-sum),
// rows 49..63 = 0. Address: bh*131072 + n4*1024 + 512 + hb*256 + (16+m5i)*8.
__global__ __launch_bounds__(256) void cvt_bf16(
    const float* __restrict__ x,  const float* __restrict__ wq,
    const float* __restrict__ wk, const float* __restrict__ wv,
    const float* __restrict__ wo,
    bf16* __restrict__ xb, bf16* __restrict__ wqkvb, bf16* __restrict__ wob,
    bf16* __restrict__ vfp)
{
  const int job = blockIdx.y;
  if (job == 5) {
    for (int u = blockIdx.x * 256 + threadIdx.x; u < 64 * 128 * 32;
         u += gridDim.x * 256) {
      const int m5i = u & 15, hb = (u >> 4) & 1, n4 = (u >> 5) & 127,
                bh = u >> 12;
      const short fill = (m5i == 0) ? (short)0x3F80 : (short)0;
      const bf16x8 o = {fill, fill, fill, fill, fill, fill, fill, fill};
      *(bf16x8*)(vfp + (size_t)bh * 131072 + n4 * 1024 + 512 + hb * 256 +
                 (16 + m5i) * 8) = o;
    }
    return;
  }
  const float* src; bf16* dst; int n;
  if (job == 0)      { src = x;  dst = xb;              n = B_ * N_ * C_; }
  else if (job == 1) { src = wq; dst = wqkvb;           n = C_ * C_; }
  else if (job == 2) { src = wk; dst = wqkvb + C_ * C_; n = C_ * C_; }
  else if (job == 3) { src = wv; dst = wqkvb + 2 * C_ * C_; n = C_ * C_; }
  else               { src = wo; dst = wob;             n = C_ * C_; }
  const int stride = gridDim.x * 256 * 8;
  for (int i = (blockIdx.x * 256 + threadIdx.x) * 8; i < n; i += stride)
    *(uint4*)(dst + i) = ld8f_cvt(src + i);
}

// ---- Kernel 1: fused QKV GEMM, m97-style. A=xb[8192x768], B=Wqkv[2304x768].
// Epilogue writes DIRECTLY in MFMA-fragment layouts (no reshape kernel):
//  Q/K(n,d): slab + (n>>5)*1536 + (d>>4)*512 + ((d>>3)&1)*256 + (n&31)*8 + (d&7)
//  Vf (n,d): slabV + (n>>4)*1024 + (d>>5)*512 + ((n>>3)&1)*256 + (d&31)*8 + (n&7)
__global__ __launch_bounds__(256) void gemm_qkv(
    const bf16* __restrict__ A, const bf16* __restrict__ Bw,
    const float* __restrict__ bq, const float* __restrict__ bk,
    const float* __restrict__ bv,
    bf16* __restrict__ Q, bf16* __restrict__ K, bf16* __restrict__ Vf)
{
  __shared__ __align__(16) bf16 As[128 * 64];
  __shared__ __align__(16) bf16 Bs[128 * 64];

  const int tid  = threadIdx.x;
  const int lane = tid & 63, wid = tid >> 6;
  const int wm = (wid >> 1) * 64, wn = (wid & 1) * 64;
  const int row0 = blockIdx.y * 128, col0 = blockIdx.x * 128;
  const int mb = lane & 15, g4 = lane >> 4;
  const int srow = lane >> 3;                    // staging row-in-8
  const int schunk = (lane & 7) ^ (srow & 7);    // swizzled glb k-chunk

  f32x4 acc[4][4];
#pragma unroll
  for (int i = 0; i < 4; ++i)
#pragma unroll
    for (int j = 0; j < 4; ++j) acc[i][j] = (f32x4){0.f, 0.f, 0.f, 0.f};

  for (int k0 = 0; k0 < C_; k0 += 64) {
#pragma unroll
    for (int t = 0; t < 4; ++t) {
      const int rt = wid * 32 + t * 8;
      gload_lds16(A  + (size_t)(row0 + rt + srow) * C_ + k0 + schunk * 8,
                  As + rt * 64);
      gload_lds16(Bw + (size_t)(col0 + rt + srow) * C_ + k0 + schunk * 8,
                  Bs + rt * 64);
    }
    __syncthreads();
#pragma unroll
    for (int ks = 0; ks < 2; ++ks) {
      const int kchunk = ks * 4 + g4;
      bf16x8 af[4], bfr[4];
#pragma unroll
      for (int i = 0; i < 4; ++i) {
        const int row = wm + i * 16 + mb;
        af[i] = *(const bf16x8*)(As + row * 64 + (kchunk ^ (row & 7)) * 8);
      }
#pragma unroll
      for (int j = 0; j < 4; ++j) {
        const int col = wn + j * 16 + mb;
        bfr[j] = *(const bf16x8*)(Bs + col * 64 + (kchunk ^ (col & 7)) * 8);
      }
#pragma unroll
      for (int i = 0; i < 4; ++i)
#pragma unroll
        for (int j = 0; j < 4; ++j)
          acc[i][j] = __builtin_amdgcn_mfma_f32_16x16x32_bf16(af[i], bfr[j], acc[i][j], 0, 0, 0);
    }
    __syncthreads();
  }

  const int z = blockIdx.x / 6;                  // 768/128=6 blocks per proj
  const int b_ = row0 >> 11;
  const int nb = (row0 & (N_ - 1)) + wm;         // local-n base of this wave
  if (z < 2) {                                   // ---- Q or K
    const float* bias = (z == 0) ? bq : bk;
    bf16* dst = (z == 0) ? Q : K;
    const float sc = (z == 0) ? (SCALE_ * LOG2E_) : 1.0f;
#pragma unroll
    for (int j = 0; j < 4; ++j) {
      const int oo = col0 - z * 768 + wn + j * 16 + mb;
      const int h = oo / D_, d = oo % D_;
      const float bb = bias[oo];
      bf16* slabp = dst + (size_t)(b_ * H_ + h) * (N_ * D_);
      const int dpart = (d >> 4) * 512 + ((d >> 3) & 1) * 256 + (d & 7);
#pragma unroll
      for (int i = 0; i < 4; ++i) {
        const int base2 = ((nb >> 5) + (i >> 1)) * 1536 + dpart;
        const int mlo = (i & 1) * 16 + g4 * 4;
#pragma unroll
        for (int reg = 0; reg < 4; ++reg)
          slabp[base2 + (mlo + reg) * 8] =
              __float2bfloat16((acc[i][j][reg] + bb) * sc);
      }
    }
  } else {                                       // ---- V -> Vf (8B stores)
#pragma unroll
    for (int j = 0; j < 4; ++j) {
      const int oo = col0 - 2 * 768 + wn + j * 16 + mb;
      const int h = oo / D_, d = oo % D_;
      const float bb = bv[oo];
      bf16* slabp = Vf + (size_t)(b_ * H_ + h) * (N_ * 64);
      const int dpart = (d >> 5) * 512 + ((g4 >> 1) * 32 + (d & 31)) * 8 +
                        (g4 & 1) * 4;
#pragma unroll
      for (int i = 0; i < 4; ++i) {
        u32x2 wv;
        wv.x = pk2(acc[i][j][0] + bb, acc[i][j][1] + bb);
        wv.y = pk2(acc[i][j][2] + bb, acc[i][j][3] + bb);
        *(u32x2*)(slabp + ((nb >> 4) + i) * 1024 + dpart) = wv;
      }
    }
  }
}

// ---- Kernel 2: LDS-staged register flash attention (round-3 structure).
// 4 waves/block share one bh slab: K/V tiles (64 keys = 14 x 1KB chunks) are
// staged ONCE per block via global_load_lds (double-buffered, prefetch
// distance 1 tile), then each wave ds_reads its fragments.
__global__ __launch_bounds__(256, 4) void attn_mfma(
    const bf16* __restrict__ Qf, const bf16* __restrict__ Kf,
    const bf16* __restrict__ Vf, const float* __restrict__ x,
    bf16* __restrict__ Yb)
{
  __shared__ __align__(16) bf16 Ls[2 * 7168];    // 2 bufs x (6KB K + 8KB V)

  const int tid  = threadIdx.x;
  const int lane = tid & 63, wid = tid >> 6;
  const int m5 = lane & 31, hi = lane >> 5;
  const int bh = blockIdx.x;
  const int b_ = bh >> 4, h = bh & 15;
  const int q0 = blockIdx.y * 128 + wid * 32;
  const size_t slab  = (size_t)bh * (N_ * D_);
  const size_t slabV = (size_t)bh * (N_ * 64);

  // Q fragments (32 q rows x 48 d), live whole kernel
  bf16x8 qf[3];
  const int kgq = q0 >> 5;
#pragma unroll
  for (int kc = 0; kc < 3; ++kc)
    qf[kc] = *(const bf16x8*)(Qf + slab + (size_t)(((kgq * 3 + kc) * 64) + lane) * 8);

  f32x16 zf;
#pragma unroll
  for (int r = 0; r < 16; ++r) zf[r] = 0.f;

  f32x16 Oacc[2];
#pragma unroll
  for (int dt = 0; dt < 2; ++dt)
#pragma unroll
    for (int r = 0; r < 16; ++r) Oacc[dt][r] = 0.f;

  // stage tile t (64 keys) into buffer buf: chunks 0-5 = K (6KB), 6-13 = V (8KB)
  const bf16* kb = Kf + slab  + (size_t)lane * 8;
  const bf16* vb = Vf + slabV + (size_t)lane * 8;
  auto stage = [&](int t, int buf) {
    bf16* dstb = Ls + buf * 7168;
    const bf16* kt = kb + (size_t)t * 3072;
    const bf16* vt = vb + (size_t)t * 4096;
    for (int c = wid; c < 14; c += 4) {
      if (c < 6) gload_lds16(kt + c * 512, dstb + c * 512);
      else       gload_lds16(vt + (c - 6) * 512, dstb + c * 512);
    }
  };

  // compute one 32-key sub-tile from LDS buffer buf
  auto sub = [&](int buf, int s) {
    const bf16* Lb = Ls + buf * 7168 + (size_t)lane * 8;
    bf16x8 kf[3], vA[2][2];
#pragma unroll
    for (int kc = 0; kc < 3; ++kc)
      kf[kc] = *(const bf16x8*)(Lb + (s * 3 + kc) * 512);
#pragma unroll
    for (int ks = 0; ks < 2; ++ks)
#pragma unroll
      for (int dt = 0; dt < 2; ++dt)
        vA[ks][dt] = *(const bf16x8*)(Lb + (6 + s * 4 + ks * 2 + dt) * 512);
    f32x16 S;
    S = __builtin_amdgcn_mfma_f32_32x32x16_bf16(kf[0], qf[0], zf, 0, 0, 0);
    S = __builtin_amdgcn_mfma_f32_32x32x16_bf16(kf[1], qf[1], S, 0, 0, 0);
    S = __builtin_amdgcn_mfma_f32_32x32x16_bf16(kf[2], qf[2], S, 0, 0, 0);
#pragma unroll
    for (int r = 0; r < 16; ++r)
      S[r] = __builtin_amdgcn_exp2f(S[r]);
    // S reg 4*qq+rr = P[q=lane&31][k32 = rr + 8*qq + 4*hi]
#pragma unroll
    for (int ks = 0; ks < 2; ++ks) {
      const int qa = ks * 2;
      const unsigned A0 = pk2(S[4 * qa + 0], S[4 * qa + 1]);
      const unsigned A1 = pk2(S[4 * qa + 2], S[4 * qa + 3]);
      const unsigned B0 = pk2(S[4 * qa + 4], S[4 * qa + 5]);
      const unsigned B1 = pk2(S[4 * qa + 6], S[4 * qa + 7]);
      const u32x2 r02 = __builtin_amdgcn_permlane32_swap(A0, B0, false, false);
      const u32x2 r13 = __builtin_amdgcn_permlane32_swap(A1, B1, false, false);
      u32x4 pw;
      pw.x = r02.x; pw.y = r13.x; pw.z = r02.y; pw.w = r13.y;
      const bf16x8 pb = (bf16x8)pw;
      Oacc[0] = __builtin_amdgcn_mfma_f32_32x32x16_bf16(vA[ks][0], pb, Oacc[0], 0, 0, 0);
      Oacc[1] = __builtin_amdgcn_mfma_f32_32x32x16_bf16(vA[ks][1], pb, Oacc[1], 0, 0, 0);
    }
  };

  stage(0, 0);
  __syncthreads();
  int buf = 0;
#pragma unroll 1
  for (int t = 0; t < 32; ++t) {
    if (t + 1 < 32) stage(t + 1, buf ^ 1);     // prefetch next tile first
    sub(buf, 0);
    sub(buf, 1);
    __syncthreads();                           // drains vmcnt: next buf ready
    buf ^= 1;
  }

  // L[q] lives in Oacc[1] row 16 = reg 8 of hi=0 lanes; broadcast to hi=1.
  const float lf = Oacc[1][8];
  const unsigned lu = __builtin_bit_cast(unsigned, lf);
  const u32x2 lsw = __builtin_amdgcn_permlane32_swap(lu, lu, false, false);
  const float Lv = __builtin_bit_cast(float, lsw.x);
  const float inv = 1.f / Lv;

  const int n = q0 + m5;
  const size_t rowoff = ((size_t)(b_ * N_ + n)) * C_ + h * D_;
#pragma unroll
  for (int qq = 0; qq < 4; ++qq) {
    const size_t off = rowoff + 8 * qq + 4 * hi;      // d = 8qq+4hi .. +3
    const float4 xr = *(const float4*)(x + off);
    u32x2 wv;
    wv.x = pk2(Oacc[0][4 * qq + 0] * inv + xr.x, Oacc[0][4 * qq + 1] * inv + xr.y);
    wv.y = pk2(Oacc[0][4 * qq + 2] * inv + xr.z, Oacc[0][4 * qq + 3] * inv + xr.w);
    *(u32x2*)(Yb + off) = wv;
  }
#pragma unroll
  for (int qq = 0; qq < 2; ++qq) {
    const size_t off = rowoff + 32 + 8 * qq + 4 * hi; // d = 32+8qq+4hi .. +3
    const float4 xr = *(const float4*)(x + off);
    u32x2 wv;
    wv.x = pk2(Oacc[1][4 * qq + 0] * inv + xr.x, Oacc[1][4 * qq + 1] * inv + xr.y);
    wv.y = pk2(Oacc[1][4 * qq + 2] * inv + xr.z, Oacc[1][4 * qq + 3] * inv + xr.w);
    *(u32x2*)(Yb + off) = wv;
  }
}

// ---- Kernel 3: O projection + residuals, m97-style staging.
// out[r][o] = acc + bo[o] + float(Yb[r][o]) + x[r][o]
__global__ __launch_bounds__(256) void gemm_out(
    const bf16* __restrict__ Yb, const bf16* __restrict__ Bw,
    const float* __restrict__ bo, const float* __restrict__ x,
    float* __restrict__ out)
{
  __shared__ __align__(16) bf16 As[128 * 64];
  __shared__ __align__(16) bf16 Bs[128 * 64];

  const int tid  = threadIdx.x;
  const int lane = tid & 63, wid = tid >> 6;
  const int wm = (wid >> 1) * 64, wn = (wid & 1) * 64;
  const int row0 = blockIdx.y * 128, col0 = blockIdx.x * 128;
  const int mb = lane & 15, g4 = lane >> 4;
  const int srow = lane >> 3;
  const int schunk = (lane & 7) ^ (srow & 7);

  f32x4 acc[4][4];
#pragma unroll
  for (int i = 0; i < 4; ++i)
#pragma unroll
    for (int j = 0; j < 4; ++j) acc[i][j] = (f32x4){0.f, 0.f, 0.f, 0.f};

  for (int k0 = 0; k0 < C_; k0 += 64) {
#pragma unroll
    for (int t = 0; t < 4; ++t) {
      const int rt = wid * 32 + t * 8;
      gload_lds16(Yb + (size_t)(row0 + rt + srow) * C_ + k0 + schunk * 8,
                  As + rt * 64);
      gload_lds16(Bw + (size_t)(col0 + rt + srow) * C_ + k0 + schunk * 8,
                  Bs + rt * 64);
    }
    __syncthreads();
#pragma unroll
    for (int ks = 0; ks < 2; ++ks) {
      const int kchunk = ks * 4 + g4;
      bf16x8 af[4], bfr[4];
#pragma unroll
      for (int i = 0; i < 4; ++i) {
        const int row = wm + i * 16 + mb;
        af[i] = *(const bf16x8*)(As + row * 64 + (kchunk ^ (row & 7)) * 8);
      }
#pragma unroll
      for (int j = 0; j < 4; ++j) {
        const int col = wn + j * 16 + mb;
        bfr[j] = *(const bf16x8*)(Bs + col * 64 + (kchunk ^ (col & 7)) * 8);
      }
#pragma unroll
      for (int i = 0; i < 4; ++i)
#pragma unroll
        for (int j = 0; j < 4; ++j)
          acc[i][j] = __builtin_amdgcn_mfma_f32_16x16x32_bf16(af[i], bfr[j], acc[i][j], 0, 0, 0);
    }
    __syncthreads();
  }

  const int crow = g4 * 4;
#pragma unroll
  for (int j = 0; j < 4; ++j) {
    const int o = col0 + wn + j * 16 + mb;
    const float bb = bo[o];
#pragma unroll
    for (int i = 0; i < 4; ++i) {
#pragma unroll
      for (int reg = 0; reg < 4; ++reg) {
        const int r = row0 + wm + i * 16 + crow + reg;
        const size_t off = (size_t)r * C_ + o;
        out[off] = acc[i][j][reg] + bb + __bfloat162float(Yb[off]) + x[off];
      }
    }
  }
}

extern "C" void kernel_launch(void* const* d_in, const int* in_sizes, int n_in,
                              void* d_out, int out_size, void* d_ws, size_t ws_size,
                              hipStream_t stream)
{
  const float* x  = (const float*)d_in[0];
  const float* wq = (const float*)d_in[1];
  const float* bq = (const float*)d_in[2];
  const float* wk = (const float*)d_in[3];
  const float* bk = (const float*)d_in[4];
  const float* wv = (const float*)d_in[5];
  const float* bv = (const float*)d_in[6];
  const float* wo = (const float*)d_in[7];
  const float* bo = (const float*)d_in[8];
  float* out = (float*)d_out;

  const size_t nEl  = (size_t)B_ * N_ * C_;      // 6,291,456
  const size_t wEl  = (size_t)C_ * C_;           // 589,824
  const size_t vfEl = (size_t)B_ * H_ * N_ * 64; // 8,388,608 (padded V frags)
  bf16* Q     = (bf16*)d_ws;                     // fragment layouts
  bf16* K     = Q + nEl;
  bf16* Vf    = K + nEl;                         // padded V A-fragment layout
  bf16* Yb    = Vf + vfEl;                       // y = attn+x, bf16
  bf16* xb    = Yb + nEl;                        // [8192][768] bf16
  bf16* wqkvb = xb + nEl;                        // [2304][768] bf16 stacked
  bf16* wob   = wqkvb + 3 * wEl;                 // [768][768] bf16

  dim3 gcvt(768, 6);                             // job 5 = Vf pad fill
  cvt_bf16<<<gcvt, dim3(256), 0, stream>>>(x, wq, wk, wv, wo, xb, wqkvb, wob, Vf);

  dim3 gqkv(18, 64);                             // 2304/128 x 8192/128
  gemm_qkv<<<gqkv, dim3(256), 0, stream>>>(xb, wqkvb, bq, bk, bv, Q, K, Vf);

  dim3 gattn(B_ * H_, N_ / 128);                 // (64, 16)
  attn_mfma<<<gattn, dim3(256), 0, stream>>>(Q, K, Vf, x, Yb);

  dim3 gout(6, 64);                              // 768/128 x 8192/128
  gemm_out<<<gout, dim3(256), 0, stream>>>(Yb, wob, bo, x, out);
}

// Round 6
// 243.526 us; speedup vs baseline: 1.0758x; 1.0291x over previous
//
#include <hip/hip_runtime.h>
#include <hip/hip_bf16.h>

// B=4, N=2048, C=768, H=16, D=48. FP32 in/out.
// Pipeline: cvt(x,W->bf16, Vf-pad) -> gemm_qkv (fused, writes Q/K/V directly in
//           MFMA-fragment layouts) -> attn (LDS-staged K/V, QBLK=64/wave to
//           halve LDS read amplification; all-register P) -> gemm_out.
#define B_ 4
#define N_ 2048
#define C_ 768
#define H_ 16
#define D_ 48
#define SCALE_ 0.14433756729740643f
#define LOG2E_ 1.44269504088896f

using bf16 = __hip_bfloat16;
using bf16x8 = __attribute__((ext_vector_type(8))) short;
using f32x4  = __attribute__((ext_vector_type(4))) float;
using f32x16 = __attribute__((ext_vector_type(16))) float;
using u32x2  = __attribute__((ext_vector_type(2))) unsigned int;
using u32x4  = __attribute__((ext_vector_type(4))) unsigned int;

__device__ __forceinline__ unsigned short f2b(float f) {
  bf16 h = __float2bfloat16(f);
  return *reinterpret_cast<unsigned short*>(&h);
}
__device__ __forceinline__ unsigned int pack2(float lo, float hi) {
  return (unsigned int)f2b(lo) | ((unsigned int)f2b(hi) << 16);
}
// packed f32->bf16 (RNE), single instruction
__device__ __forceinline__ unsigned int pk2(float lo, float hi) {
  unsigned int r;
  asm("v_cvt_pk_bf16_f32 %0, %1, %2" : "=v"(r) : "v"(lo), "v"(hi));
  return r;
}
__device__ __forceinline__ uint4 ld8f_cvt(const float* p) {
  float4 a = *reinterpret_cast<const float4*>(p);
  float4 b = *reinterpret_cast<const float4*>(p + 4);
  uint4 u;
  u.x = pack2(a.x, a.y); u.y = pack2(a.z, a.w);
  u.z = pack2(b.x, b.y); u.w = pack2(b.z, b.w);
  return u;
}
// async global->LDS, 16B per lane; LDS dest = wave-uniform base + lane*16B
__device__ __forceinline__ void gload_lds16(const bf16* g, bf16* l) {
  __builtin_amdgcn_global_load_lds(
      (const __attribute__((address_space(1))) unsigned int*)g,
      (__attribute__((address_space(3))) unsigned int*)l, 16, 0, 0);
}

// ---- Kernel 0: fp32 -> bf16 conversions + static Vf pad fill.
// Fragment-layout pad of Vf (d-rows 48..63): row 48 = 1.0 (fused L row-sum),
// rows 49..63 = 0. Address: bh*131072 + n4*1024 + 512 + hb*256 + (16+m5i)*8.
__global__ __launch_bounds__(256) void cvt_bf16(
    const float* __restrict__ x,  const float* __restrict__ wq,
    const float* __restrict__ wk, const float* __restrict__ wv,
    const float* __restrict__ wo,
    bf16* __restrict__ xb, bf16* __restrict__ wqkvb, bf16* __restrict__ wob,
    bf16* __restrict__ vfp)
{
  const int job = blockIdx.y;
  if (job == 5) {
    for (int u = blockIdx.x * 256 + threadIdx.x; u < 64 * 128 * 32;
         u += gridDim.x * 256) {
      const int m5i = u & 15, hb = (u >> 4) & 1, n4 = (u >> 5) & 127,
                bh = u >> 12;
      const short fill = (m5i == 0) ? (short)0x3F80 : (short)0;
      const bf16x8 o = {fill, fill, fill, fill, fill, fill, fill, fill};
      *(bf16x8*)(vfp + (size_t)bh * 131072 + n4 * 1024 + 512 + hb * 256 +
                 (16 + m5i) * 8) = o;
    }
    return;
  }
  const float* src; bf16* dst; int n;
  if (job == 0)      { src = x;  dst = xb;              n = B_ * N_ * C_; }
  else if (job == 1) { src = wq; dst = wqkvb;           n = C_ * C_; }
  else if (job == 2) { src = wk; dst = wqkvb + C_ * C_; n = C_ * C_; }
  else if (job == 3) { src = wv; dst = wqkvb + 2 * C_ * C_; n = C_ * C_; }
  else               { src = wo; dst = wob;             n = C_ * C_; }
  const int stride = gridDim.x * 256 * 8;
  for (int i = (blockIdx.x * 256 + threadIdx.x) * 8; i < n; i += stride)
    *(uint4*)(dst + i) = ld8f_cvt(src + i);
}

// ---- Kernel 1: fused QKV GEMM, m97-style. A=xb[8192x768], B=Wqkv[2304x768].
// Epilogue writes DIRECTLY in MFMA-fragment layouts (no reshape kernel):
//  Q/K(n,d): slab + (n>>5)*1536 + (d>>4)*512 + ((d>>3)&1)*256 + (n&31)*8 + (d&7)
//  Vf (n,d): slabV + (n>>4)*1024 + (d>>5)*512 + ((n>>3)&1)*256 + (d&31)*8 + (n&7)
__global__ __launch_bounds__(256) void gemm_qkv(
    const bf16* __restrict__ A, const bf16* __restrict__ Bw,
    const float* __restrict__ bq, const float* __restrict__ bk,
    const float* __restrict__ bv,
    bf16* __restrict__ Q, bf16* __restrict__ K, bf16* __restrict__ Vf)
{
  __shared__ __align__(16) bf16 As[128 * 64];
  __shared__ __align__(16) bf16 Bs[128 * 64];

  const int tid  = threadIdx.x;
  const int lane = tid & 63, wid = tid >> 6;
  const int wm = (wid >> 1) * 64, wn = (wid & 1) * 64;
  const int row0 = blockIdx.y * 128, col0 = blockIdx.x * 128;
  const int mb = lane & 15, g4 = lane >> 4;
  const int srow = lane >> 3;                    // staging row-in-8
  const int schunk = (lane & 7) ^ (srow & 7);    // swizzled glb k-chunk

  f32x4 acc[4][4];
#pragma unroll
  for (int i = 0; i < 4; ++i)
#pragma unroll
    for (int j = 0; j < 4; ++j) acc[i][j] = (f32x4){0.f, 0.f, 0.f, 0.f};

  for (int k0 = 0; k0 < C_; k0 += 64) {
#pragma unroll
    for (int t = 0; t < 4; ++t) {
      const int rt = wid * 32 + t * 8;
      gload_lds16(A  + (size_t)(row0 + rt + srow) * C_ + k0 + schunk * 8,
                  As + rt * 64);
      gload_lds16(Bw + (size_t)(col0 + rt + srow) * C_ + k0 + schunk * 8,
                  Bs + rt * 64);
    }
    __syncthreads();
#pragma unroll
    for (int ks = 0; ks < 2; ++ks) {
      const int kchunk = ks * 4 + g4;
      bf16x8 af[4], bfr[4];
#pragma unroll
      for (int i = 0; i < 4; ++i) {
        const int row = wm + i * 16 + mb;
        af[i] = *(const bf16x8*)(As + row * 64 + (kchunk ^ (row & 7)) * 8);
      }
#pragma unroll
      for (int j = 0; j < 4; ++j) {
        const int col = wn + j * 16 + mb;
        bfr[j] = *(const bf16x8*)(Bs + col * 64 + (kchunk ^ (col & 7)) * 8);
      }
#pragma unroll
      for (int i = 0; i < 4; ++i)
#pragma unroll
        for (int j = 0; j < 4; ++j)
          acc[i][j] = __builtin_amdgcn_mfma_f32_16x16x32_bf16(af[i], bfr[j], acc[i][j], 0, 0, 0);
    }
    __syncthreads();
  }

  const int z = blockIdx.x / 6;                  // 768/128=6 blocks per proj
  const int b_ = row0 >> 11;
  const int nb = (row0 & (N_ - 1)) + wm;         // local-n base of this wave
  if (z < 2) {                                   // ---- Q or K
    const float* bias = (z == 0) ? bq : bk;
    bf16* dst = (z == 0) ? Q : K;
    const float sc = (z == 0) ? (SCALE_ * LOG2E_) : 1.0f;
#pragma unroll
    for (int j = 0; j < 4; ++j) {
      const int oo = col0 - z * 768 + wn + j * 16 + mb;
      const int h = oo / D_, d = oo % D_;
      const float bb = bias[oo];
      bf16* slabp = dst + (size_t)(b_ * H_ + h) * (N_ * D_);
      const int dpart = (d >> 4) * 512 + ((d >> 3) & 1) * 256 + (d & 7);
#pragma unroll
      for (int i = 0; i < 4; ++i) {
        const int base2 = ((nb >> 5) + (i >> 1)) * 1536 + dpart;
        const int mlo = (i & 1) * 16 + g4 * 4;
#pragma unroll
        for (int reg = 0; reg < 4; ++reg)
          slabp[base2 + (mlo + reg) * 8] =
              __float2bfloat16((acc[i][j][reg] + bb) * sc);
      }
    }
  } else {                                       // ---- V -> Vf (8B stores)
#pragma unroll
    for (int j = 0; j < 4; ++j) {
      const int oo = col0 - 2 * 768 + wn + j * 16 + mb;
      const int h = oo / D_, d = oo % D_;
      const float bb = bv[oo];
      bf16* slabp = Vf + (size_t)(b_ * H_ + h) * (N_ * 64);
      const int dpart = (d >> 5) * 512 + ((g4 >> 1) * 32 + (d & 31)) * 8 +
                        (g4 & 1) * 4;
#pragma unroll
      for (int i = 0; i < 4; ++i) {
        u32x2 wv;
        wv.x = pk2(acc[i][j][0] + bb, acc[i][j][1] + bb);
        wv.y = pk2(acc[i][j][2] + bb, acc[i][j][3] + bb);
        *(u32x2*)(slabp + ((nb >> 4) + i) * 1024 + dpart) = wv;
      }
    }
  }
}

// ---- Kernel 2: LDS-staged register flash attention, QBLK=64 per wave.
// 4 waves/block, 256 q rows/block; each 14KB K/V LDS tile read feeds TWO
// 32-q-row MFMA sets (halves LDS read amplification vs QBLK=32).
// Double-buffered global_load_lds prefetch, barrier-drained (round-3 proven).
__global__ __launch_bounds__(256, 2) void attn_mfma(
    const bf16* __restrict__ Qf, const bf16* __restrict__ Kf,
    const bf16* __restrict__ Vf, const float* __restrict__ x,
    bf16* __restrict__ Yb)
{
  __shared__ __align__(16) bf16 Ls[2 * 7168];    // 2 bufs x (6KB K + 8KB V)

  const int tid  = threadIdx.x;
  const int lane = tid & 63, wid = tid >> 6;
  const int m5 = lane & 31, hi = lane >> 5;
  const int bh = blockIdx.x;
  const int b_ = bh >> 4, h = bh & 15;
  const int q0 = blockIdx.y * 256 + wid * 64;    // 64 q rows per wave
  const size_t slab  = (size_t)bh * (N_ * D_);
  const size_t slabV = (size_t)bh * (N_ * 64);

  // Q fragments for both 32-row halves, live whole kernel
  bf16x8 qfA[3], qfB[3];
  const int kgq = q0 >> 5;
#pragma unroll
  for (int kc = 0; kc < 3; ++kc) {
    qfA[kc] = *(const bf16x8*)(Qf + slab + (size_t)(((kgq * 3 + kc) * 64) + lane) * 8);
    qfB[kc] = *(const bf16x8*)(Qf + slab + (size_t)((((kgq + 1) * 3 + kc) * 64) + lane) * 8);
  }

  f32x16 zf;
#pragma unroll
  for (int r = 0; r < 16; ++r) zf[r] = 0.f;

  f32x16 OA[2], OB[2];
#pragma unroll
  for (int dt = 0; dt < 2; ++dt)
#pragma unroll
    for (int r = 0; r < 16; ++r) { OA[dt][r] = 0.f; OB[dt][r] = 0.f; }

  // stage tile t (64 keys) into buffer buf: chunks 0-5 = K (6KB), 6-13 = V (8KB)
  const bf16* kb = Kf + slab  + (size_t)lane * 8;
  const bf16* vb = Vf + slabV + (size_t)lane * 8;
  auto stage = [&](int t, int buf) {
    bf16* dstb = Ls + buf * 7168;
    const bf16* kt = kb + (size_t)t * 3072;
    const bf16* vt = vb + (size_t)t * 4096;
    for (int c = wid; c < 14; c += 4) {
      if (c < 6) gload_lds16(kt + c * 512, dstb + c * 512);
      else       gload_lds16(vt + (c - 6) * 512, dstb + c * 512);
    }
  };

  // softmax + PV for one 32-q-row half (S consumed; one S live at a time)
  auto smpv = [&](f32x16& S, f32x16& O0, f32x16& O1, bf16x8 (&vA)[2][2]) {
#pragma unroll
    for (int r = 0; r < 16; ++r)
      S[r] = __builtin_amdgcn_exp2f(S[r]);
    // S reg 4*qq+rr = P[q=lane&31][k32 = rr + 8*qq + 4*hi]
#pragma unroll
    for (int ks = 0; ks < 2; ++ks) {
      const int qa = ks * 2;
      const unsigned A0 = pk2(S[4 * qa + 0], S[4 * qa + 1]);
      const unsigned A1 = pk2(S[4 * qa + 2], S[4 * qa + 3]);
      const unsigned B0 = pk2(S[4 * qa + 4], S[4 * qa + 5]);
      const unsigned B1 = pk2(S[4 * qa + 6], S[4 * qa + 7]);
      const u32x2 r02 = __builtin_amdgcn_permlane32_swap(A0, B0, false, false);
      const u32x2 r13 = __builtin_amdgcn_permlane32_swap(A1, B1, false, false);
      u32x4 pw;
      pw.x = r02.x; pw.y = r13.x; pw.z = r02.y; pw.w = r13.y;
      const bf16x8 pb = (bf16x8)pw;
      O0 = __builtin_amdgcn_mfma_f32_32x32x16_bf16(vA[ks][0], pb, O0, 0, 0, 0);
      O1 = __builtin_amdgcn_mfma_f32_32x32x16_bf16(vA[ks][1], pb, O1, 0, 0, 0);
    }
  };

  // compute one 32-key sub-tile (both q-halves) from LDS buffer buf
  auto sub = [&](int buf, int s) {
    const bf16* Lb = Ls + buf * 7168 + (size_t)lane * 8;
    bf16x8 kf[3], vA[2][2];
#pragma unroll
    for (int kc = 0; kc < 3; ++kc)
      kf[kc] = *(const bf16x8*)(Lb + (s * 3 + kc) * 512);
#pragma unroll
    for (int ks = 0; ks < 2; ++ks)
#pragma unroll
      for (int dt = 0; dt < 2; ++dt)
        vA[ks][dt] = *(const bf16x8*)(Lb + (6 + s * 4 + ks * 2 + dt) * 512);
    {
      f32x16 S;
      S = __builtin_amdgcn_mfma_f32_32x32x16_bf16(kf[0], qfA[0], zf, 0, 0, 0);
      S = __builtin_amdgcn_mfma_f32_32x32x16_bf16(kf[1], qfA[1], S, 0, 0, 0);
      S = __builtin_amdgcn_mfma_f32_32x32x16_bf16(kf[2], qfA[2], S, 0, 0, 0);
      smpv(S, OA[0], OA[1], vA);
    }
    {
      f32x16 S;
      S = __builtin_amdgcn_mfma_f32_32x32x16_bf16(kf[0], qfB[0], zf, 0, 0, 0);
      S = __builtin_amdgcn_mfma_f32_32x32x16_bf16(kf[1], qfB[1], S, 0, 0, 0);
      S = __builtin_amdgcn_mfma_f32_32x32x16_bf16(kf[2], qfB[2], S, 0, 0, 0);
      smpv(S, OB[0], OB[1], vA);
    }
  };

  stage(0, 0);
  __syncthreads();
  int buf = 0;
#pragma unroll 1
  for (int t = 0; t < 32; ++t) {
    if (t + 1 < 32) stage(t + 1, buf ^ 1);     // prefetch next tile first
    sub(buf, 0);
    sub(buf, 1);
    __syncthreads();                           // drains vmcnt: next buf ready
    buf ^= 1;
  }

  // Epilogue per half. L[q] = O1 row 16 = reg 8 of hi=0 lanes; bcast to hi=1.
  auto epi = [&](const f32x16& O0, const f32x16& O1, int qbase) {
    const float lf = O1[8];
    const unsigned lu = __builtin_bit_cast(unsigned, lf);
    const u32x2 lsw = __builtin_amdgcn_permlane32_swap(lu, lu, false, false);
    const float Lv = __builtin_bit_cast(float, lsw.x);
    const float inv = 1.f / Lv;
    const int n = qbase + m5;
    const size_t rowoff = ((size_t)(b_ * N_ + n)) * C_ + h * D_;
#pragma unroll
    for (int qq = 0; qq < 4; ++qq) {
      const size_t off = rowoff + 8 * qq + 4 * hi;      // d = 8qq+4hi .. +3
      const float4 xr = *(const float4*)(x + off);
      u32x2 wv;
      wv.x = pk2(O0[4 * qq + 0] * inv + xr.x, O0[4 * qq + 1] * inv + xr.y);
      wv.y = pk2(O0[4 * qq + 2] * inv + xr.z, O0[4 * qq + 3] * inv + xr.w);
      *(u32x2*)(Yb + off) = wv;
    }
#pragma unroll
    for (int qq = 0; qq < 2; ++qq) {
      const size_t off = rowoff + 32 + 8 * qq + 4 * hi; // d = 32+8qq+4hi .. +3
      const float4 xr = *(const float4*)(x + off);
      u32x2 wv;
      wv.x = pk2(O1[4 * qq + 0] * inv + xr.x, O1[4 * qq + 1] * inv + xr.y);
      wv.y = pk2(O1[4 * qq + 2] * inv + xr.z, O1[4 * qq + 3] * inv + xr.w);
      *(u32x2*)(Yb + off) = wv;
    }
  };
  epi(OA[0], OA[1], q0);
  epi(OB[0], OB[1], q0 + 32);
}

// ---- Kernel 3: O projection + residuals, m97-style staging.
// out[r][o] = acc + bo[o] + float(Yb[r][o]) + x[r][o]
__global__ __launch_bounds__(256) void gemm_out(
    const bf16* __restrict__ Yb, const bf16* __restrict__ Bw,
    const float* __restrict__ bo, const float* __restrict__ x,
    float* __restrict__ out)
{
  __shared__ __align__(16) bf16 As[128 * 64];
  __shared__ __align__(16) bf16 Bs[128 * 64];

  const int tid  = threadIdx.x;
  const int lane = tid & 63, wid = tid >> 6;
  const int wm = (wid >> 1) * 64, wn = (wid & 1) * 64;
  const int row0 = blockIdx.y * 128, col0 = blockIdx.x * 128;
  const int mb = lane & 15, g4 = lane >> 4;
  const int srow = lane >> 3;
  const int schunk = (lane & 7) ^ (srow & 7);

  f32x4 acc[4][4];
#pragma unroll
  for (int i = 0; i < 4; ++i)
#pragma unroll
    for (int j = 0; j < 4; ++j) acc[i][j] = (f32x4){0.f, 0.f, 0.f, 0.f};

  for (int k0 = 0; k0 < C_; k0 += 64) {
#pragma unroll
    for (int t = 0; t < 4; ++t) {
      const int rt = wid * 32 + t * 8;
      gload_lds16(Yb + (size_t)(row0 + rt + srow) * C_ + k0 + schunk * 8,
                  As + rt * 64);
      gload_lds16(Bw + (size_t)(col0 + rt + srow) * C_ + k0 + schunk * 8,
                  Bs + rt * 64);
    }
    __syncthreads();
#pragma unroll
    for (int ks = 0; ks < 2; ++ks) {
      const int kchunk = ks * 4 + g4;
      bf16x8 af[4], bfr[4];
#pragma unroll
      for (int i = 0; i < 4; ++i) {
        const int row = wm + i * 16 + mb;
        af[i] = *(const bf16x8*)(As + row * 64 + (kchunk ^ (row & 7)) * 8);
      }
#pragma unroll
      for (int j = 0; j < 4; ++j) {
        const int col = wn + j * 16 + mb;
        bfr[j] = *(const bf16x8*)(Bs + col * 64 + (kchunk ^ (col & 7)) * 8);
      }
#pragma unroll
      for (int i = 0; i < 4; ++i)
#pragma unroll
        for (int j = 0; j < 4; ++j)
          acc[i][j] = __builtin_amdgcn_mfma_f32_16x16x32_bf16(af[i], bfr[j], acc[i][j], 0, 0, 0);
    }
    __syncthreads();
  }

  const int crow = g4 * 4;
#pragma unroll
  for (int j = 0; j < 4; ++j) {
    const int o = col0 + wn + j * 16 + mb;
    const float bb = bo[o];
#pragma unroll
    for (int i = 0; i < 4; ++i) {
#pragma unroll
      for (int reg = 0; reg < 4; ++reg) {
        const int r = row0 + wm + i * 16 + crow + reg;
        const size_t off = (size_t)r * C_ + o;
        out[off] = acc[i][j][reg] + bb + __bfloat162float(Yb[off]) + x[off];
      }
    }
  }
}

extern "C" void kernel_launch(void* const* d_in, const int* in_sizes, int n_in,
                              void* d_out, int out_size, void* d_ws, size_t ws_size,
                              hipStream_t stream)
{
  const float* x  = (const float*)d_in[0];
  const float* wq = (const float*)d_in[1];
  const float* bq = (const float*)d_in[2];
  const float* wk = (const float*)d_in[3];
  const float* bk = (const float*)d_in[4];
  const float* wv = (const float*)d_in[5];
  const float* bv = (const float*)d_in[6];
  const float* wo = (const float*)d_in[7];
  const float* bo = (const float*)d_in[8];
  float* out = (float*)d_out;

  const size_t nEl  = (size_t)B_ * N_ * C_;      // 6,291,456
  const size_t wEl  = (size_t)C_ * C_;           // 589,824
  const size_t vfEl = (size_t)B_ * H_ * N_ * 64; // 8,388,608 (padded V frags)
  bf16* Q     = (bf16*)d_ws;                     // fragment layouts
  bf16* K     = Q + nEl;
  bf16* Vf    = K + nEl;                         // padded V A-fragment layout
  bf16* Yb    = Vf + vfEl;                       // y = attn+x, bf16
  bf16* xb    = Yb + nEl;                        // [8192][768] bf16
  bf16* wqkvb = xb + nEl;                        // [2304][768] bf16 stacked
  bf16* wob   = wqkvb + 3 * wEl;                 // [768][768] bf16

  dim3 gcvt(768, 6);                             // job 5 = Vf pad fill
  cvt_bf16<<<gcvt, dim3(256), 0, stream>>>(x, wq, wk, wv, wo, xb, wqkvb, wob, Vf);

  dim3 gqkv(18, 64);                             // 2304/128 x 8192/128
  gemm_qkv<<<gqkv, dim3(256), 0, stream>>>(xb, wqkvb, bq, bk, bv, Q, K, Vf);

  dim3 gattn(B_ * H_, N_ / 256);                 // (64, 8), QBLK=64/wave
  attn_mfma<<<gattn, dim3(256), 0, stream>>>(Q, K, Vf, x, Yb);

  dim3 gout(6, 64);                              // 768/128 x 8192/128
  gemm_out<<<gout, dim3(256), 0, stream>>>(Yb, wob, bo, x, out);
}

// Round 7
// 226.853 us; speedup vs baseline: 1.1549x; 1.0735x over previous
//
#include <hip/hip_runtime.h>
#include <hip/hip_bf16.h>

// B=4, N=2048, C=768, H=16, D=48. FP32 in/out.
// Pipeline: cvt(x,W->bf16, Vf-pad) -> gemm_qkv (fused, swapped-operand MFMA for
//           Q/K -> 8B vector epilogue stores; direct fragment layouts) ->
//           attn (LDS-staged K/V, QBLK=64/wave) -> gemm_out (swapped-operand
//           MFMA -> float4 epilogue).
#define B_ 4
#define N_ 2048
#define C_ 768
#define H_ 16
#define D_ 48
#define SCALE_ 0.14433756729740643f
#define LOG2E_ 1.44269504088896f

using bf16 = __hip_bfloat16;
using bf16x8 = __attribute__((ext_vector_type(8))) short;
using f32x4  = __attribute__((ext_vector_type(4))) float;
using f32x16 = __attribute__((ext_vector_type(16))) float;
using u32x2  = __attribute__((ext_vector_type(2))) unsigned int;
using u32x4  = __attribute__((ext_vector_type(4))) unsigned int;

__device__ __forceinline__ unsigned short f2b(float f) {
  bf16 h = __float2bfloat16(f);
  return *reinterpret_cast<unsigned short*>(&h);
}
__device__ __forceinline__ unsigned int pack2(float lo, float hi) {
  return (unsigned int)f2b(lo) | ((unsigned int)f2b(hi) << 16);
}
// packed f32->bf16 (RNE), single instruction
__device__ __forceinline__ unsigned int pk2(float lo, float hi) {
  unsigned int r;
  asm("v_cvt_pk_bf16_f32 %0, %1, %2" : "=v"(r) : "v"(lo), "v"(hi));
  return r;
}
// bf16 (as u16) -> f32 exact
__device__ __forceinline__ float b2f(unsigned short us) {
  return __builtin_bit_cast(float, (unsigned)us << 16);
}
__device__ __forceinline__ uint4 ld8f_cvt(const float* p) {
  float4 a = *reinterpret_cast<const float4*>(p);
  float4 b = *reinterpret_cast<const float4*>(p + 4);
  uint4 u;
  u.x = pack2(a.x, a.y); u.y = pack2(a.z, a.w);
  u.z = pack2(b.x, b.y); u.w = pack2(b.z, b.w);
  return u;
}
// async global->LDS, 16B per lane; LDS dest = wave-uniform base + lane*16B
__device__ __forceinline__ void gload_lds16(const bf16* g, bf16* l) {
  __builtin_amdgcn_global_load_lds(
      (const __attribute__((address_space(1))) unsigned int*)g,
      (__attribute__((address_space(3))) unsigned int*)l, 16, 0, 0);
}

// ---- Kernel 0: fp32 -> bf16 conversions + static Vf pad fill.
__global__ __launch_bounds__(256) void cvt_bf16(
    const float* __restrict__ x,  const float* __restrict__ wq,
    const float* __restrict__ wk, const float* __restrict__ wv,
    const float* __restrict__ wo,
    bf16* __restrict__ xb, bf16* __restrict__ wqkvb, bf16* __restrict__ wob,
    bf16* __restrict__ vfp)
{
  const int job = blockIdx.y;
  if (job == 5) {
    for (int u = blockIdx.x * 256 + threadIdx.x; u < 64 * 128 * 32;
         u += gridDim.x * 256) {
      const int m5i = u & 15, hb = (u >> 4) & 1, n4 = (u >> 5) & 127,
                bh = u >> 12;
      const short fill = (m5i == 0) ? (short)0x3F80 : (short)0;
      const bf16x8 o = {fill, fill, fill, fill, fill, fill, fill, fill};
      *(bf16x8*)(vfp + (size_t)bh * 131072 + n4 * 1024 + 512 + hb * 256 +
                 (16 + m5i) * 8) = o;
    }
    return;
  }
  const float* src; bf16* dst; int n;
  if (job == 0)      { src = x;  dst = xb;              n = B_ * N_ * C_; }
  else if (job == 1) { src = wq; dst = wqkvb;           n = C_ * C_; }
  else if (job == 2) { src = wk; dst = wqkvb + C_ * C_; n = C_ * C_; }
  else if (job == 3) { src = wv; dst = wqkvb + 2 * C_ * C_; n = C_ * C_; }
  else               { src = wo; dst = wob;             n = C_ * C_; }
  const int stride = gridDim.x * 256 * 8;
  for (int i = (blockIdx.x * 256 + threadIdx.x) * 8; i < n; i += stride)
    *(uint4*)(dst + i) = ld8f_cvt(src + i);
}

// ---- Kernel 1: fused QKV GEMM, m97-style. A=xb[8192x768], B=Wqkv[2304x768].
// Q/K blocks use SWAPPED MFMA operands: D^T layout puts 4 consecutive d per
// thread -> one 8B store per (i,j). V keeps original order (consecutive n).
//  Q/K(n,d): slab + (n>>5)*1536 + (d>>4)*512 + ((d>>3)&1)*256 + (n&31)*8 + (d&7)
//  Vf (n,d): slabV + (n>>4)*1024 + (d>>5)*512 + ((n>>3)&1)*256 + (d&31)*8 + (n&7)
__global__ __launch_bounds__(256) void gemm_qkv(
    const bf16* __restrict__ A, const bf16* __restrict__ Bw,
    const float* __restrict__ bq, const float* __restrict__ bk,
    const float* __restrict__ bv,
    bf16* __restrict__ Q, bf16* __restrict__ K, bf16* __restrict__ Vf)
{
  __shared__ __align__(16) bf16 As[128 * 64];
  __shared__ __align__(16) bf16 Bs[128 * 64];

  const int tid  = threadIdx.x;
  const int lane = tid & 63, wid = tid >> 6;
  const int wm = (wid >> 1) * 64, wn = (wid & 1) * 64;
  const int row0 = blockIdx.y * 128, col0 = blockIdx.x * 128;
  const int mb = lane & 15, g4 = lane >> 4;
  const int srow = lane >> 3;                    // staging row-in-8
  const int schunk = (lane & 7) ^ (srow & 7);    // swizzled glb k-chunk
  const int z = blockIdx.x / 6;                  // 768/128=6 blocks per proj

  f32x4 acc[4][4];
#pragma unroll
  for (int i = 0; i < 4; ++i)
#pragma unroll
    for (int j = 0; j < 4; ++j) acc[i][j] = (f32x4){0.f, 0.f, 0.f, 0.f};

  auto kloop = [&](bool swapped) {
    for (int k0 = 0; k0 < C_; k0 += 64) {
#pragma unroll
      for (int t = 0; t < 4; ++t) {
        const int rt = wid * 32 + t * 8;
        gload_lds16(A  + (size_t)(row0 + rt + srow) * C_ + k0 + schunk * 8,
                    As + rt * 64);
        gload_lds16(Bw + (size_t)(col0 + rt + srow) * C_ + k0 + schunk * 8,
                    Bs + rt * 64);
      }
      __syncthreads();
#pragma unroll
      for (int ks = 0; ks < 2; ++ks) {
        const int kchunk = ks * 4 + g4;
        bf16x8 af[4], bfr[4];
#pragma unroll
        for (int i = 0; i < 4; ++i) {
          const int row = wm + i * 16 + mb;
          af[i] = *(const bf16x8*)(As + row * 64 + (kchunk ^ (row & 7)) * 8);
        }
#pragma unroll
        for (int j = 0; j < 4; ++j) {
          const int col = wn + j * 16 + mb;
          bfr[j] = *(const bf16x8*)(Bs + col * 64 + (kchunk ^ (col & 7)) * 8);
        }
        if (swapped) {
#pragma unroll
          for (int i = 0; i < 4; ++i)
#pragma unroll
            for (int j = 0; j < 4; ++j)
              acc[i][j] = __builtin_amdgcn_mfma_f32_16x16x32_bf16(bfr[j], af[i], acc[i][j], 0, 0, 0);
        } else {
#pragma unroll
          for (int i = 0; i < 4; ++i)
#pragma unroll
            for (int j = 0; j < 4; ++j)
              acc[i][j] = __builtin_amdgcn_mfma_f32_16x16x32_bf16(af[i], bfr[j], acc[i][j], 0, 0, 0);
        }
      }
      __syncthreads();
    }
  };

  const int b_ = row0 >> 11;
  const int nb = (row0 & (N_ - 1)) + wm;         // local-n base of this wave
  if (z < 2) {                                   // ---- Q or K (swapped D^T)
    kloop(true);
    const float* bias = (z == 0) ? bq : bk;
    bf16* dst = (z == 0) ? Q : K;
    const float sc = (z == 0) ? (SCALE_ * LOG2E_) : 1.0f;
    // D^T: col(lane&15)=n-side (af), row(g4*4+reg)=feature-side (bfr)
#pragma unroll
    for (int j = 0; j < 4; ++j) {
      const int c = col0 - z * 768 + wn + j * 16 + g4 * 4;  // 4 consecutive feats
      const int h = c / D_, d0 = c % D_;          // 4|48: no head crossing
      const float4 bb = *(const float4*)(bias + c);
      bf16* slabp = dst + (size_t)(b_ * H_ + h) * (N_ * D_);
      const int dpart = (d0 >> 4) * 512 + ((d0 >> 3) & 1) * 256 + (d0 & 7);
#pragma unroll
      for (int i = 0; i < 4; ++i) {
        const int n = nb + i * 16 + mb;
        u32x2 wv;
        wv.x = pk2((acc[i][j][0] + bb.x) * sc, (acc[i][j][1] + bb.y) * sc);
        wv.y = pk2((acc[i][j][2] + bb.z) * sc, (acc[i][j][3] + bb.w) * sc);
        *(u32x2*)(slabp + (n >> 5) * 1536 + dpart + (n & 31) * 8) = wv;
      }
    }
  } else {                                       // ---- V -> Vf (orig order)
    kloop(false);
#pragma unroll
    for (int j = 0; j < 4; ++j) {
      const int oo = col0 - 2 * 768 + wn + j * 16 + mb;
      const int h = oo / D_, d = oo % D_;
      const float bb = bv[oo];
      bf16* slabp = Vf + (size_t)(b_ * H_ + h) * (N_ * 64);
      const int dpart = (d >> 5) * 512 + ((g4 >> 1) * 32 + (d & 31)) * 8 +
                        (g4 & 1) * 4;
#pragma unroll
      for (int i = 0; i < 4; ++i) {
        u32x2 wv;
        wv.x = pk2(acc[i][j][0] + bb, acc[i][j][1] + bb);
        wv.y = pk2(acc[i][j][2] + bb, acc[i][j][3] + bb);
        *(u32x2*)(slabp + ((nb >> 4) + i) * 1024 + dpart) = wv;
      }
    }
  }
}

// ---- Kernel 2: LDS-staged register flash attention, QBLK=64 per wave.
// (round-6 proven structure, unchanged)
__global__ __launch_bounds__(256, 2) void attn_mfma(
    const bf16* __restrict__ Qf, const bf16* __restrict__ Kf,
    const bf16* __restrict__ Vf, const float* __restrict__ x,
    bf16* __restrict__ Yb)
{
  __shared__ __align__(16) bf16 Ls[2 * 7168];    // 2 bufs x (6KB K + 8KB V)

  const int tid  = threadIdx.x;
  const int lane = tid & 63, wid = tid >> 6;
  const int m5 = lane & 31, hi = lane >> 5;
  const int bh = blockIdx.x;
  const int b_ = bh >> 4, h = bh & 15;
  const int q0 = blockIdx.y * 256 + wid * 64;    // 64 q rows per wave
  const size_t slab  = (size_t)bh * (N_ * D_);
  const size_t slabV = (size_t)bh * (N_ * 64);

  bf16x8 qfA[3], qfB[3];
  const int kgq = q0 >> 5;
#pragma unroll
  for (int kc = 0; kc < 3; ++kc) {
    qfA[kc] = *(const bf16x8*)(Qf + slab + (size_t)(((kgq * 3 + kc) * 64) + lane) * 8);
    qfB[kc] = *(const bf16x8*)(Qf + slab + (size_t)((((kgq + 1) * 3 + kc) * 64) + lane) * 8);
  }

  f32x16 zf;
#pragma unroll
  for (int r = 0; r < 16; ++r) zf[r] = 0.f;

  f32x16 OA[2], OB[2];
#pragma unroll
  for (int dt = 0; dt < 2; ++dt)
#pragma unroll
    for (int r = 0; r < 16; ++r) { OA[dt][r] = 0.f; OB[dt][r] = 0.f; }

  const bf16* kb = Kf + slab  + (size_t)lane * 8;
  const bf16* vb = Vf + slabV + (size_t)lane * 8;
  auto stage = [&](int t, int buf) {
    bf16* dstb = Ls + buf * 7168;
    const bf16* kt = kb + (size_t)t * 3072;
    const bf16* vt = vb + (size_t)t * 4096;
    for (int c = wid; c < 14; c += 4) {
      if (c < 6) gload_lds16(kt + c * 512, dstb + c * 512);
      else       gload_lds16(vt + (c - 6) * 512, dstb + c * 512);
    }
  };

  auto smpv = [&](f32x16& S, f32x16& O0, f32x16& O1, bf16x8 (&vA)[2][2]) {
#pragma unroll
    for (int r = 0; r < 16; ++r)
      S[r] = __builtin_amdgcn_exp2f(S[r]);
#pragma unroll
    for (int ks = 0; ks < 2; ++ks) {
      const int qa = ks * 2;
      const unsigned A0 = pk2(S[4 * qa + 0], S[4 * qa + 1]);
      const unsigned A1 = pk2(S[4 * qa + 2], S[4 * qa + 3]);
      const unsigned B0 = pk2(S[4 * qa + 4], S[4 * qa + 5]);
      const unsigned B1 = pk2(S[4 * qa + 6], S[4 * qa + 7]);
      const u32x2 r02 = __builtin_amdgcn_permlane32_swap(A0, B0, false, false);
      const u32x2 r13 = __builtin_amdgcn_permlane32_swap(A1, B1, false, false);
      u32x4 pw;
      pw.x = r02.x; pw.y = r13.x; pw.z = r02.y; pw.w = r13.y;
      const bf16x8 pb = (bf16x8)pw;
      O0 = __builtin_amdgcn_mfma_f32_32x32x16_bf16(vA[ks][0], pb, O0, 0, 0, 0);
      O1 = __builtin_amdgcn_mfma_f32_32x32x16_bf16(vA[ks][1], pb, O1, 0, 0, 0);
    }
  };

  auto sub = [&](int buf, int s) {
    const bf16* Lb = Ls + buf * 7168 + (size_t)lane * 8;
    bf16x8 kf[3], vA[2][2];
#pragma unroll
    for (int kc = 0; kc < 3; ++kc)
      kf[kc] = *(const bf16x8*)(Lb + (s * 3 + kc) * 512);
#pragma unroll
    for (int ks = 0; ks < 2; ++ks)
#pragma unroll
      for (int dt = 0; dt < 2; ++dt)
        vA[ks][dt] = *(const bf16x8*)(Lb + (6 + s * 4 + ks * 2 + dt) * 512);
    {
      f32x16 S;
      S = __builtin_amdgcn_mfma_f32_32x32x16_bf16(kf[0], qfA[0], zf, 0, 0, 0);
      S = __builtin_amdgcn_mfma_f32_32x32x16_bf16(kf[1], qfA[1], S, 0, 0, 0);
      S = __builtin_amdgcn_mfma_f32_32x32x16_bf16(kf[2], qfA[2], S, 0, 0, 0);
      smpv(S, OA[0], OA[1], vA);
    }
    {
      f32x16 S;
      S = __builtin_amdgcn_mfma_f32_32x32x16_bf16(kf[0], qfB[0], zf, 0, 0, 0);
      S = __builtin_amdgcn_mfma_f32_32x32x16_bf16(kf[1], qfB[1], S, 0, 0, 0);
      S = __builtin_amdgcn_mfma_f32_32x32x16_bf16(kf[2], qfB[2], S, 0, 0, 0);
      smpv(S, OB[0], OB[1], vA);
    }
  };

  stage(0, 0);
  __syncthreads();
  int buf = 0;
#pragma unroll 1
  for (int t = 0; t < 32; ++t) {
    if (t + 1 < 32) stage(t + 1, buf ^ 1);     // prefetch next tile first
    sub(buf, 0);
    sub(buf, 1);
    __syncthreads();                           // drains vmcnt: next buf ready
    buf ^= 1;
  }

  auto epi = [&](const f32x16& O0, const f32x16& O1, int qbase) {
    const float lf = O1[8];
    const unsigned lu = __builtin_bit_cast(unsigned, lf);
    const u32x2 lsw = __builtin_amdgcn_permlane32_swap(lu, lu, false, false);
    const float Lv = __builtin_bit_cast(float, lsw.x);
    const float inv = 1.f / Lv;
    const int n = qbase + m5;
    const size_t rowoff = ((size_t)(b_ * N_ + n)) * C_ + h * D_;
#pragma unroll
    for (int qq = 0; qq < 4; ++qq) {
      const size_t off = rowoff + 8 * qq + 4 * hi;      // d = 8qq+4hi .. +3
      const float4 xr = *(const float4*)(x + off);
      u32x2 wv;
      wv.x = pk2(O0[4 * qq + 0] * inv + xr.x, O0[4 * qq + 1] * inv + xr.y);
      wv.y = pk2(O0[4 * qq + 2] * inv + xr.z, O0[4 * qq + 3] * inv + xr.w);
      *(u32x2*)(Yb + off) = wv;
    }
#pragma unroll
    for (int qq = 0; qq < 2; ++qq) {
      const size_t off = rowoff + 32 + 8 * qq + 4 * hi; // d = 32+8qq+4hi .. +3
      const float4 xr = *(const float4*)(x + off);
      u32x2 wv;
      wv.x = pk2(O1[4 * qq + 0] * inv + xr.x, O1[4 * qq + 1] * inv + xr.y);
      wv.y = pk2(O1[4 * qq + 2] * inv + xr.z, O1[4 * qq + 3] * inv + xr.w);
      *(u32x2*)(Yb + off) = wv;
    }
  };
  epi(OA[0], OA[1], q0);
  epi(OB[0], OB[1], q0 + 32);
}

// ---- Kernel 3: O projection + residuals, SWAPPED MFMA operands:
// thread owns 4 consecutive o at fixed r -> float4 loads/stores.
// out[r][o] = acc + bo[o] + float(Yb[r][o]) + x[r][o]
__global__ __launch_bounds__(256) void gemm_out(
    const bf16* __restrict__ Yb, const bf16* __restrict__ Bw,
    const float* __restrict__ bo, const float* __restrict__ x,
    float* __restrict__ out)
{
  __shared__ __align__(16) bf16 As[128 * 64];
  __shared__ __align__(16) bf16 Bs[128 * 64];

  const int tid  = threadIdx.x;
  const int lane = tid & 63, wid = tid >> 6;
  const int wm = (wid >> 1) * 64, wn = (wid & 1) * 64;
  const int row0 = blockIdx.y * 128, col0 = blockIdx.x * 128;
  const int mb = lane & 15, g4 = lane >> 4;
  const int srow = lane >> 3;
  const int schunk = (lane & 7) ^ (srow & 7);

  f32x4 acc[4][4];
#pragma unroll
  for (int i = 0; i < 4; ++i)
#pragma unroll
    for (int j = 0; j < 4; ++j) acc[i][j] = (f32x4){0.f, 0.f, 0.f, 0.f};

  for (int k0 = 0; k0 < C_; k0 += 64) {
#pragma unroll
    for (int t = 0; t < 4; ++t) {
      const int rt = wid * 32 + t * 8;
      gload_lds16(Yb + (size_t)(row0 + rt + srow) * C_ + k0 + schunk * 8,
                  As + rt * 64);
      gload_lds16(Bw + (size_t)(col0 + rt + srow) * C_ + k0 + schunk * 8,
                  Bs + rt * 64);
    }
    __syncthreads();
#pragma unroll
    for (int ks = 0; ks < 2; ++ks) {
      const int kchunk = ks * 4 + g4;
      bf16x8 af[4], bfr[4];
#pragma unroll
      for (int i = 0; i < 4; ++i) {
        const int row = wm + i * 16 + mb;
        af[i] = *(const bf16x8*)(As + row * 64 + (kchunk ^ (row & 7)) * 8);
      }
#pragma unroll
      for (int j = 0; j < 4; ++j) {
        const int col = wn + j * 16 + mb;
        bfr[j] = *(const bf16x8*)(Bs + col * 64 + (kchunk ^ (col & 7)) * 8);
      }
#pragma unroll
      for (int i = 0; i < 4; ++i)
#pragma unroll
        for (int j = 0; j < 4; ++j)
          acc[i][j] = __builtin_amdgcn_mfma_f32_16x16x32_bf16(bfr[j], af[i], acc[i][j], 0, 0, 0);
    }
    __syncthreads();
  }

  // D^T: col(lane&15)=r-side (af rows), row(g4*4+reg)=o-side (bfr rows)
#pragma unroll
  for (int j = 0; j < 4; ++j) {
    const int o0 = col0 + wn + j * 16 + g4 * 4;
    const float4 bb = *(const float4*)(bo + o0);
#pragma unroll
    for (int i = 0; i < 4; ++i) {
      const int r = row0 + wm + i * 16 + mb;
      const size_t off = (size_t)r * C_ + o0;
      const u32x2 yv = *(const u32x2*)(Yb + off);   // 4 bf16
      const float4 xr = *(const float4*)(x + off);
      float4 ov;
      ov.x = acc[i][j][0] + bb.x + b2f((unsigned short)(yv.x & 0xffff)) + xr.x;
      ov.y = acc[i][j][1] + bb.y + b2f((unsigned short)(yv.x >> 16))    + xr.y;
      ov.z = acc[i][j][2] + bb.z + b2f((unsigned short)(yv.y & 0xffff)) + xr.z;
      ov.w = acc[i][j][3] + bb.w + b2f((unsigned short)(yv.y >> 16))    + xr.w;
      *(float4*)(out + off) = ov;
    }
  }
}

extern "C" void kernel_launch(void* const* d_in, const int* in_sizes, int n_in,
                              void* d_out, int out_size, void* d_ws, size_t ws_size,
                              hipStream_t stream)
{
  const float* x  = (const float*)d_in[0];
  const float* wq = (const float*)d_in[1];
  const float* bq = (const float*)d_in[2];
  const float* wk = (const float*)d_in[3];
  const float* bk = (const float*)d_in[4];
  const float* wv = (const float*)d_in[5];
  const float* bv = (const float*)d_in[6];
  const float* wo = (const float*)d_in[7];
  const float* bo = (const float*)d_in[8];
  float* out = (float*)d_out;

  const size_t nEl  = (size_t)B_ * N_ * C_;      // 6,291,456
  const size_t wEl  = (size_t)C_ * C_;           // 589,824
  const size_t vfEl = (size_t)B_ * H_ * N_ * 64; // 8,388,608 (padded V frags)
  bf16* Q     = (bf16*)d_ws;                     // fragment layouts
  bf16* K     = Q + nEl;
  bf16* Vf    = K + nEl;                         // padded V A-fragment layout
  bf16* Yb    = Vf + vfEl;                       // y = attn+x, bf16
  bf16* xb    = Yb + nEl;                        // [8192][768] bf16
  bf16* wqkvb = xb + nEl;                        // [2304][768] bf16 stacked
  bf16* wob   = wqkvb + 3 * wEl;                 // [768][768] bf16

  dim3 gcvt(768, 6);                             // job 5 = Vf pad fill
  cvt_bf16<<<gcvt, dim3(256), 0, stream>>>(x, wq, wk, wv, wo, xb, wqkvb, wob, Vf);

  dim3 gqkv(18, 64);                             // 2304/128 x 8192/128
  gemm_qkv<<<gqkv, dim3(256), 0, stream>>>(xb, wqkvb, bq, bk, bv, Q, K, Vf);

  dim3 gattn(B_ * H_, N_ / 256);                 // (64, 8), QBLK=64/wave
  attn_mfma<<<gattn, dim3(256), 0, stream>>>(Q, K, Vf, x, Yb);

  dim3 gout(6, 64);                              // 768/128 x 8192/128
  gemm_out<<<gout, dim3(256), 0, stream>>>(Yb, wob, bo, x, out);
}

// Round 8
// 225.103 us; speedup vs baseline: 1.1639x; 1.0078x over previous
//
#include <hip/hip_runtime.h>
#include <hip/hip_bf16.h>

// B=4, N=2048, C=768, H=16, D=48. FP32 in/out.
// Pipeline: cvt(x,W->bf16, Vf-pad) -> gemm_qkv (fused, XCD-swizzled, swapped-
//           operand MFMA for Q/K; direct fragment layouts) -> attn (LDS-staged
//           K/V, QBLK=64/wave, interleaved A/B chains) -> gemm_out (XCD-
//           swizzled, swapped-operand MFMA, float4 epilogue).
#define B_ 4
#define N_ 2048
#define C_ 768
#define H_ 16
#define D_ 48
#define SCALE_ 0.14433756729740643f
#define LOG2E_ 1.44269504088896f

using bf16 = __hip_bfloat16;
using bf16x8 = __attribute__((ext_vector_type(8))) short;
using f32x4  = __attribute__((ext_vector_type(4))) float;
using f32x16 = __attribute__((ext_vector_type(16))) float;
using u32x2  = __attribute__((ext_vector_type(2))) unsigned int;
using u32x4  = __attribute__((ext_vector_type(4))) unsigned int;

__device__ __forceinline__ unsigned short f2b(float f) {
  bf16 h = __float2bfloat16(f);
  return *reinterpret_cast<unsigned short*>(&h);
}
__device__ __forceinline__ unsigned int pack2(float lo, float hi) {
  return (unsigned int)f2b(lo) | ((unsigned int)f2b(hi) << 16);
}
// packed f32->bf16 (RNE), single instruction
__device__ __forceinline__ unsigned int pk2(float lo, float hi) {
  unsigned int r;
  asm("v_cvt_pk_bf16_f32 %0, %1, %2" : "=v"(r) : "v"(lo), "v"(hi));
  return r;
}
// bf16 (as u16) -> f32 exact
__device__ __forceinline__ float b2f(unsigned short us) {
  return __builtin_bit_cast(float, (unsigned)us << 16);
}
__device__ __forceinline__ uint4 ld8f_cvt(const float* p) {
  float4 a = *reinterpret_cast<const float4*>(p);
  float4 b = *reinterpret_cast<const float4*>(p + 4);
  uint4 u;
  u.x = pack2(a.x, a.y); u.y = pack2(a.z, a.w);
  u.z = pack2(b.x, b.y); u.w = pack2(b.z, b.w);
  return u;
}
// async global->LDS, 16B per lane; LDS dest = wave-uniform base + lane*16B
__device__ __forceinline__ void gload_lds16(const bf16* g, bf16* l) {
  __builtin_amdgcn_global_load_lds(
      (const __attribute__((address_space(1))) unsigned int*)g,
      (__attribute__((address_space(3))) unsigned int*)l, 16, 0, 0);
}

// ---- Kernel 0: fp32 -> bf16 conversions + static Vf pad fill.
__global__ __launch_bounds__(256) void cvt_bf16(
    const float* __restrict__ x,  const float* __restrict__ wq,
    const float* __restrict__ wk, const float* __restrict__ wv,
    const float* __restrict__ wo,
    bf16* __restrict__ xb, bf16* __restrict__ wqkvb, bf16* __restrict__ wob,
    bf16* __restrict__ vfp)
{
  const int job = blockIdx.y;
  if (job == 5) {
    for (int u = blockIdx.x * 256 + threadIdx.x; u < 64 * 128 * 32;
         u += gridDim.x * 256) {
      const int m5i = u & 15, hb = (u >> 4) & 1, n4 = (u >> 5) & 127,
                bh = u >> 12;
      const short fill = (m5i == 0) ? (short)0x3F80 : (short)0;
      const bf16x8 o = {fill, fill, fill, fill, fill, fill, fill, fill};
      *(bf16x8*)(vfp + (size_t)bh * 131072 + n4 * 1024 + 512 + hb * 256 +
                 (16 + m5i) * 8) = o;
    }
    return;
  }
  const float* src; bf16* dst; int n;
  if (job == 0)      { src = x;  dst = xb;              n = B_ * N_ * C_; }
  else if (job == 1) { src = wq; dst = wqkvb;           n = C_ * C_; }
  else if (job == 2) { src = wk; dst = wqkvb + C_ * C_; n = C_ * C_; }
  else if (job == 3) { src = wv; dst = wqkvb + 2 * C_ * C_; n = C_ * C_; }
  else               { src = wo; dst = wob;             n = C_ * C_; }
  const int stride = gridDim.x * 256 * 8;
  for (int i = (blockIdx.x * 256 + threadIdx.x) * 8; i < n; i += stride)
    *(uint4*)(dst + i) = ld8f_cvt(src + i);
}

// ---- Kernel 1: fused QKV GEMM, m97-style, XCD-chunked block swizzle.
// Q/K blocks use SWAPPED MFMA operands -> 8B vector epilogue stores.
//  Q/K(n,d): slab + (n>>5)*1536 + (d>>4)*512 + ((d>>3)&1)*256 + (n&31)*8 + (d&7)
//  Vf (n,d): slabV + (n>>4)*1024 + (d>>5)*512 + ((n>>3)&1)*256 + (d&31)*8 + (n&7)
__global__ __launch_bounds__(256) void gemm_qkv(
    const bf16* __restrict__ A, const bf16* __restrict__ Bw,
    const float* __restrict__ bq, const float* __restrict__ bk,
    const float* __restrict__ bv,
    bf16* __restrict__ Q, bf16* __restrict__ K, bf16* __restrict__ Vf)
{
  __shared__ __align__(16) bf16 As[128 * 64];
  __shared__ __align__(16) bf16 Bs[128 * 64];

  // XCD-chunked swizzle: nwg=1152=8*144. XCD k (= lid%8) processes 144
  // consecutive tiles = 8 full row-panels x 18 cols -> A 1.6MB + B 3.5MB / L2.
  const int lid  = blockIdx.x + 18 * blockIdx.y;
  const int nlid = (lid & 7) * 144 + (lid >> 3);
  const int bx = nlid % 18, by = nlid / 18;

  const int tid  = threadIdx.x;
  const int lane = tid & 63, wid = tid >> 6;
  const int wm = (wid >> 1) * 64, wn = (wid & 1) * 64;
  const int row0 = by * 128, col0 = bx * 128;
  const int mb = lane & 15, g4 = lane >> 4;
  const int srow = lane >> 3;                    // staging row-in-8
  const int schunk = (lane & 7) ^ (srow & 7);    // swizzled glb k-chunk
  const int z = bx / 6;                          // 768/128=6 blocks per proj

  f32x4 acc[4][4];
#pragma unroll
  for (int i = 0; i < 4; ++i)
#pragma unroll
    for (int j = 0; j < 4; ++j) acc[i][j] = (f32x4){0.f, 0.f, 0.f, 0.f};

  auto kloop = [&](bool swapped) {
    for (int k0 = 0; k0 < C_; k0 += 64) {
#pragma unroll
      for (int t = 0; t < 4; ++t) {
        const int rt = wid * 32 + t * 8;
        gload_lds16(A  + (size_t)(row0 + rt + srow) * C_ + k0 + schunk * 8,
                    As + rt * 64);
        gload_lds16(Bw + (size_t)(col0 + rt + srow) * C_ + k0 + schunk * 8,
                    Bs + rt * 64);
      }
      __syncthreads();
#pragma unroll
      for (int ks = 0; ks < 2; ++ks) {
        const int kchunk = ks * 4 + g4;
        bf16x8 af[4], bfr[4];
#pragma unroll
        for (int i = 0; i < 4; ++i) {
          const int row = wm + i * 16 + mb;
          af[i] = *(const bf16x8*)(As + row * 64 + (kchunk ^ (row & 7)) * 8);
        }
#pragma unroll
        for (int j = 0; j < 4; ++j) {
          const int col = wn + j * 16 + mb;
          bfr[j] = *(const bf16x8*)(Bs + col * 64 + (kchunk ^ (col & 7)) * 8);
        }
        if (swapped) {
#pragma unroll
          for (int i = 0; i < 4; ++i)
#pragma unroll
            for (int j = 0; j < 4; ++j)
              acc[i][j] = __builtin_amdgcn_mfma_f32_16x16x32_bf16(bfr[j], af[i], acc[i][j], 0, 0, 0);
        } else {
#pragma unroll
          for (int i = 0; i < 4; ++i)
#pragma unroll
            for (int j = 0; j < 4; ++j)
              acc[i][j] = __builtin_amdgcn_mfma_f32_16x16x32_bf16(af[i], bfr[j], acc[i][j], 0, 0, 0);
        }
      }
      __syncthreads();
    }
  };

  const int b_ = row0 >> 11;
  const int nb = (row0 & (N_ - 1)) + wm;         // local-n base of this wave
  if (z < 2) {                                   // ---- Q or K (swapped D^T)
    kloop(true);
    const float* bias = (z == 0) ? bq : bk;
    bf16* dst = (z == 0) ? Q : K;
    const float sc = (z == 0) ? (SCALE_ * LOG2E_) : 1.0f;
    // D^T: col(lane&15)=n-side (af), row(g4*4+reg)=feature-side (bfr)
#pragma unroll
    for (int j = 0; j < 4; ++j) {
      const int c = col0 - z * 768 + wn + j * 16 + g4 * 4;  // 4 consecutive feats
      const int h = c / D_, d0 = c % D_;          // 4|48: no head crossing
      const float4 bb = *(const float4*)(bias + c);
      bf16* slabp = dst + (size_t)(b_ * H_ + h) * (N_ * D_);
      const int dpart = (d0 >> 4) * 512 + ((d0 >> 3) & 1) * 256 + (d0 & 7);
#pragma unroll
      for (int i = 0; i < 4; ++i) {
        const int n = nb + i * 16 + mb;
        u32x2 wv;
        wv.x = pk2((acc[i][j][0] + bb.x) * sc, (acc[i][j][1] + bb.y) * sc);
        wv.y = pk2((acc[i][j][2] + bb.z) * sc, (acc[i][j][3] + bb.w) * sc);
        *(u32x2*)(slabp + (n >> 5) * 1536 + dpart + (n & 31) * 8) = wv;
      }
    }
  } else {                                       // ---- V -> Vf (orig order)
    kloop(false);
#pragma unroll
    for (int j = 0; j < 4; ++j) {
      const int oo = col0 - 2 * 768 + wn + j * 16 + mb;
      const int h = oo / D_, d = oo % D_;
      const float bb = bv[oo];
      bf16* slabp = Vf + (size_t)(b_ * H_ + h) * (N_ * 64);
      const int dpart = (d >> 5) * 512 + ((g4 >> 1) * 32 + (d & 31)) * 8 +
                        (g4 & 1) * 4;
#pragma unroll
      for (int i = 0; i < 4; ++i) {
        u32x2 wv;
        wv.x = pk2(acc[i][j][0] + bb, acc[i][j][1] + bb);
        wv.y = pk2(acc[i][j][2] + bb, acc[i][j][3] + bb);
        *(u32x2*)(slabp + ((nb >> 4) + i) * 1024 + dpart) = wv;
      }
    }
  }
}

// ---- Kernel 2: LDS-staged register flash attention, QBLK=64 per wave.
// Both q-halves' QK^T chains issued BEFORE either softmax/PV: the B-half's
// MFMAs fill the matrix pipe while the A-half's exp/pack runs on VALU/trans.
__global__ __launch_bounds__(256, 2) void attn_mfma(
    const bf16* __restrict__ Qf, const bf16* __restrict__ Kf,
    const bf16* __restrict__ Vf, const float* __restrict__ x,
    bf16* __restrict__ Yb)
{
  __shared__ __align__(16) bf16 Ls[2 * 7168];    // 2 bufs x (6KB K + 8KB V)

  const int tid  = threadIdx.x;
  const int lane = tid & 63, wid = tid >> 6;
  const int m5 = lane & 31, hi = lane >> 5;
  const int bh = blockIdx.x;
  const int b_ = bh >> 4, h = bh & 15;
  const int q0 = blockIdx.y * 256 + wid * 64;    // 64 q rows per wave
  const size_t slab  = (size_t)bh * (N_ * D_);
  const size_t slabV = (size_t)bh * (N_ * 64);

  bf16x8 qfA[3], qfB[3];
  const int kgq = q0 >> 5;
#pragma unroll
  for (int kc = 0; kc < 3; ++kc) {
    qfA[kc] = *(const bf16x8*)(Qf + slab + (size_t)(((kgq * 3 + kc) * 64) + lane) * 8);
    qfB[kc] = *(const bf16x8*)(Qf + slab + (size_t)((((kgq + 1) * 3 + kc) * 64) + lane) * 8);
  }

  f32x16 zf;
#pragma unroll
  for (int r = 0; r < 16; ++r) zf[r] = 0.f;

  f32x16 OA[2], OB[2];
#pragma unroll
  for (int dt = 0; dt < 2; ++dt)
#pragma unroll
    for (int r = 0; r < 16; ++r) { OA[dt][r] = 0.f; OB[dt][r] = 0.f; }

  const bf16* kb = Kf + slab  + (size_t)lane * 8;
  const bf16* vb = Vf + slabV + (size_t)lane * 8;
  auto stage = [&](int t, int buf) {
    bf16* dstb = Ls + buf * 7168;
    const bf16* kt = kb + (size_t)t * 3072;
    const bf16* vt = vb + (size_t)t * 4096;
    for (int c = wid; c < 14; c += 4) {
      if (c < 6) gload_lds16(kt + c * 512, dstb + c * 512);
      else       gload_lds16(vt + (c - 6) * 512, dstb + c * 512);
    }
  };

  auto smpv = [&](f32x16& S, f32x16& O0, f32x16& O1, bf16x8 (&vA)[2][2]) {
#pragma unroll
    for (int r = 0; r < 16; ++r)
      S[r] = __builtin_amdgcn_exp2f(S[r]);
#pragma unroll
    for (int ks = 0; ks < 2; ++ks) {
      const int qa = ks * 2;
      const unsigned A0 = pk2(S[4 * qa + 0], S[4 * qa + 1]);
      const unsigned A1 = pk2(S[4 * qa + 2], S[4 * qa + 3]);
      const unsigned B0 = pk2(S[4 * qa + 4], S[4 * qa + 5]);
      const unsigned B1 = pk2(S[4 * qa + 6], S[4 * qa + 7]);
      const u32x2 r02 = __builtin_amdgcn_permlane32_swap(A0, B0, false, false);
      const u32x2 r13 = __builtin_amdgcn_permlane32_swap(A1, B1, false, false);
      u32x4 pw;
      pw.x = r02.x; pw.y = r13.x; pw.z = r02.y; pw.w = r13.y;
      const bf16x8 pb = (bf16x8)pw;
      O0 = __builtin_amdgcn_mfma_f32_32x32x16_bf16(vA[ks][0], pb, O0, 0, 0, 0);
      O1 = __builtin_amdgcn_mfma_f32_32x32x16_bf16(vA[ks][1], pb, O1, 0, 0, 0);
    }
  };

  auto sub = [&](int buf, int s) {
    const bf16* Lb = Ls + buf * 7168 + (size_t)lane * 8;
    bf16x8 kf[3], vA[2][2];
#pragma unroll
    for (int kc = 0; kc < 3; ++kc)
      kf[kc] = *(const bf16x8*)(Lb + (s * 3 + kc) * 512);
#pragma unroll
    for (int ks = 0; ks < 2; ++ks)
#pragma unroll
      for (int dt = 0; dt < 2; ++dt)
        vA[ks][dt] = *(const bf16x8*)(Lb + (6 + s * 4 + ks * 2 + dt) * 512);
    // both QK chains first (independent): B-half MFMAs overlap A-half softmax
    f32x16 SA, SB;
    SA = __builtin_amdgcn_mfma_f32_32x32x16_bf16(kf[0], qfA[0], zf, 0, 0, 0);
    SB = __builtin_amdgcn_mfma_f32_32x32x16_bf16(kf[0], qfB[0], zf, 0, 0, 0);
    SA = __builtin_amdgcn_mfma_f32_32x32x16_bf16(kf[1], qfA[1], SA, 0, 0, 0);
    SB = __builtin_amdgcn_mfma_f32_32x32x16_bf16(kf[1], qfB[1], SB, 0, 0, 0);
    SA = __builtin_amdgcn_mfma_f32_32x32x16_bf16(kf[2], qfA[2], SA, 0, 0, 0);
    SB = __builtin_amdgcn_mfma_f32_32x32x16_bf16(kf[2], qfB[2], SB, 0, 0, 0);
    smpv(SA, OA[0], OA[1], vA);
    smpv(SB, OB[0], OB[1], vA);
  };

  stage(0, 0);
  __syncthreads();
  int buf = 0;
#pragma unroll 1
  for (int t = 0; t < 32; ++t) {
    if (t + 1 < 32) stage(t + 1, buf ^ 1);     // prefetch next tile first
    sub(buf, 0);
    sub(buf, 1);
    __syncthreads();                           // drains vmcnt: next buf ready
    buf ^= 1;
  }

  auto epi = [&](const f32x16& O0, const f32x16& O1, int qbase) {
    const float lf = O1[8];
    const unsigned lu = __builtin_bit_cast(unsigned, lf);
    const u32x2 lsw = __builtin_amdgcn_permlane32_swap(lu, lu, false, false);
    const float Lv = __builtin_bit_cast(float, lsw.x);
    const float inv = 1.f / Lv;
    const int n = qbase + m5;
    const size_t rowoff = ((size_t)(b_ * N_ + n)) * C_ + h * D_;
#pragma unroll
    for (int qq = 0; qq < 4; ++qq) {
      const size_t off = rowoff + 8 * qq + 4 * hi;      // d = 8qq+4hi .. +3
      const float4 xr = *(const float4*)(x + off);
      u32x2 wv;
      wv.x = pk2(O0[4 * qq + 0] * inv + xr.x, O0[4 * qq + 1] * inv + xr.y);
      wv.y = pk2(O0[4 * qq + 2] * inv + xr.z, O0[4 * qq + 3] * inv + xr.w);
      *(u32x2*)(Yb + off) = wv;
    }
#pragma unroll
    for (int qq = 0; qq < 2; ++qq) {
      const size_t off = rowoff + 32 + 8 * qq + 4 * hi; // d = 32+8qq+4hi .. +3
      const float4 xr = *(const float4*)(x + off);
      u32x2 wv;
      wv.x = pk2(O1[4 * qq + 0] * inv + xr.x, O1[4 * qq + 1] * inv + xr.y);
      wv.y = pk2(O1[4 * qq + 2] * inv + xr.z, O1[4 * qq + 3] * inv + xr.w);
      *(u32x2*)(Yb + off) = wv;
    }
  };
  epi(OA[0], OA[1], q0);
  epi(OB[0], OB[1], q0 + 32);
}

// ---- Kernel 3: O projection + residuals, XCD-swizzled, swapped MFMA:
// thread owns 4 consecutive o at fixed r -> float4 loads/stores.
// out[r][o] = acc + bo[o] + float(Yb[r][o]) + x[r][o]
__global__ __launch_bounds__(256) void gemm_out(
    const bf16* __restrict__ Yb, const bf16* __restrict__ Bw,
    const float* __restrict__ bo, const float* __restrict__ x,
    float* __restrict__ out)
{
  __shared__ __align__(16) bf16 As[128 * 64];
  __shared__ __align__(16) bf16 Bs[128 * 64];

  // XCD-chunked swizzle: nwg=384=8*48 -> per XCD: 8 row-panels x 6 cols
  // = Yb 1.6MB + Wo 1.2MB, L2-resident.
  const int lid  = blockIdx.x + 6 * blockIdx.y;
  const int nlid = (lid & 7) * 48 + (lid >> 3);
  const int bx = nlid % 6, by = nlid / 6;

  const int tid  = threadIdx.x;
  const int lane = tid & 63, wid = tid >> 6;
  const int wm = (wid >> 1) * 64, wn = (wid & 1) * 64;
  const int row0 = by * 128, col0 = bx * 128;
  const int mb = lane & 15, g4 = lane >> 4;
  const int srow = lane >> 3;
  const int schunk = (lane & 7) ^ (srow & 7);

  f32x4 acc[4][4];
#pragma unroll
  for (int i = 0; i < 4; ++i)
#pragma unroll
    for (int j = 0; j < 4; ++j) acc[i][j] = (f32x4){0.f, 0.f, 0.f, 0.f};

  for (int k0 = 0; k0 < C_; k0 += 64) {
#pragma unroll
    for (int t = 0; t < 4; ++t) {
      const int rt = wid * 32 + t * 8;
      gload_lds16(Yb + (size_t)(row0 + rt + srow) * C_ + k0 + schunk * 8,
                  As + rt * 64);
      gload_lds16(Bw + (size_t)(col0 + rt + srow) * C_ + k0 + schunk * 8,
                  Bs + rt * 64);
    }
    __syncthreads();
#pragma unroll
    for (int ks = 0; ks < 2; ++ks) {
      const int kchunk = ks * 4 + g4;
      bf16x8 af[4], bfr[4];
#pragma unroll
      for (int i = 0; i < 4; ++i) {
        const int row = wm + i * 16 + mb;
        af[i] = *(const bf16x8*)(As + row * 64 + (kchunk ^ (row & 7)) * 8);
      }
#pragma unroll
      for (int j = 0; j < 4; ++j) {
        const int col = wn + j * 16 + mb;
        bfr[j] = *(const bf16x8*)(Bs + col * 64 + (kchunk ^ (col & 7)) * 8);
      }
#pragma unroll
      for (int i = 0; i < 4; ++i)
#pragma unroll
        for (int j = 0; j < 4; ++j)
          acc[i][j] = __builtin_amdgcn_mfma_f32_16x16x32_bf16(bfr[j], af[i], acc[i][j], 0, 0, 0);
    }
    __syncthreads();
  }

  // D^T: col(lane&15)=r-side (af rows), row(g4*4+reg)=o-side (bfr rows)
#pragma unroll
  for (int j = 0; j < 4; ++j) {
    const int o0 = col0 + wn + j * 16 + g4 * 4;
    const float4 bb = *(const float4*)(bo + o0);
#pragma unroll
    for (int i = 0; i < 4; ++i) {
      const int r = row0 + wm + i * 16 + mb;
      const size_t off = (size_t)r * C_ + o0;
      const u32x2 yv = *(const u32x2*)(Yb + off);   // 4 bf16
      const float4 xr = *(const float4*)(x + off);
      float4 ov;
      ov.x = acc[i][j][0] + bb.x + b2f((unsigned short)(yv.x & 0xffff)) + xr.x;
      ov.y = acc[i][j][1] + bb.y + b2f((unsigned short)(yv.x >> 16))    + xr.y;
      ov.z = acc[i][j][2] + bb.z + b2f((unsigned short)(yv.y & 0xffff)) + xr.z;
      ov.w = acc[i][j][3] + bb.w + b2f((unsigned short)(yv.y >> 16))    + xr.w;
      *(float4*)(out + off) = ov;
    }
  }
}

extern "C" void kernel_launch(void* const* d_in, const int* in_sizes, int n_in,
                              void* d_out, int out_size, void* d_ws, size_t ws_size,
                              hipStream_t stream)
{
  const float* x  = (const float*)d_in[0];
  const float* wq = (const float*)d_in[1];
  const float* bq = (const float*)d_in[2];
  const float* wk = (const float*)d_in[3];
  const float* bk = (const float*)d_in[4];
  const float* wv = (const float*)d_in[5];
  const float* bv = (const float*)d_in[6];
  const float* wo = (const float*)d_in[7];
  const float* bo = (const float*)d_in[8];
  float* out = (float*)d_out;

  const size_t nEl  = (size_t)B_ * N_ * C_;      // 6,291,456
  const size_t wEl  = (size_t)C_ * C_;           // 589,824
  const size_t vfEl = (size_t)B_ * H_ * N_ * 64; // 8,388,608 (padded V frags)
  bf16* Q     = (bf16*)d_ws;                     // fragment layouts
  bf16* K     = Q + nEl;
  bf16* Vf    = K + nEl;                         // padded V A-fragment layout
  bf16* Yb    = Vf + vfEl;                       // y = attn+x, bf16
  bf16* xb    = Yb + nEl;                        // [8192][768] bf16
  bf16* wqkvb = xb + nEl;                        // [2304][768] bf16 stacked
  bf16* wob   = wqkvb + 3 * wEl;                 // [768][768] bf16

  dim3 gcvt(768, 6);                             // job 5 = Vf pad fill
  cvt_bf16<<<gcvt, dim3(256), 0, stream>>>(x, wq, wk, wv, wo, xb, wqkvb, wob, Vf);

  dim3 gqkv(18, 64);                             // 2304/128 x 8192/128
  gemm_qkv<<<gqkv, dim3(256), 0, stream>>>(xb, wqkvb, bq, bk, bv, Q, K, Vf);

  dim3 gattn(B_ * H_, N_ / 256);                 // (64, 8), QBLK=64/wave
  attn_mfma<<<gattn, dim3(256), 0, stream>>>(Q, K, Vf, x, Yb);

  dim3 gout(6, 64);                              // 768/128 x 8192/128
  gemm_out<<<gout, dim3(256), 0, stream>>>(Yb, wob, bo, x, out);
}

// Round 9
// 224.998 us; speedup vs baseline: 1.1644x; 1.0005x over previous
//
#include <hip/hip_runtime.h>
#include <hip/hip_bf16.h>

// B=4, N=2048, C=768, H=16, D=48. FP32 in/out.
// Pipeline: cvt(x,W->bf16, Vf-pad) -> gemm_qkv (fused, XCD-swizzled, swapped-
//           operand MFMA for Q/K; direct fragment layouts) -> attn (LDS-staged
//           K/V, QBLK=64/wave, sequential halves [R6-proven]) -> gemm_out
//           (64x128 tile, 3 blocks/CU, XCD-swizzled, swapped-operand MFMA).
#define B_ 4
#define N_ 2048
#define C_ 768
#define H_ 16
#define D_ 48
#define SCALE_ 0.14433756729740643f
#define LOG2E_ 1.44269504088896f

using bf16 = __hip_bfloat16;
using bf16x8 = __attribute__((ext_vector_type(8))) short;
using f32x4  = __attribute__((ext_vector_type(4))) float;
using f32x16 = __attribute__((ext_vector_type(16))) float;
using u32x2  = __attribute__((ext_vector_type(2))) unsigned int;
using u32x4  = __attribute__((ext_vector_type(4))) unsigned int;

__device__ __forceinline__ unsigned short f2b(float f) {
  bf16 h = __float2bfloat16(f);
  return *reinterpret_cast<unsigned short*>(&h);
}
__device__ __forceinline__ unsigned int pack2(float lo, float hi) {
  return (unsigned int)f2b(lo) | ((unsigned int)f2b(hi) << 16);
}
// packed f32->bf16 (RNE), single instruction
__device__ __forceinline__ unsigned int pk2(float lo, float hi) {
  unsigned int r;
  asm("v_cvt_pk_bf16_f32 %0, %1, %2" : "=v"(r) : "v"(lo), "v"(hi));
  return r;
}
// bf16 (as u16) -> f32 exact
__device__ __forceinline__ float b2f(unsigned short us) {
  return __builtin_bit_cast(float, (unsigned)us << 16);
}
__device__ __forceinline__ uint4 ld8f_cvt(const float* p) {
  float4 a = *reinterpret_cast<const float4*>(p);
  float4 b = *reinterpret_cast<const float4*>(p + 4);
  uint4 u;
  u.x = pack2(a.x, a.y); u.y = pack2(a.z, a.w);
  u.z = pack2(b.x, b.y); u.w = pack2(b.z, b.w);
  return u;
}
// async global->LDS, 16B per lane; LDS dest = wave-uniform base + lane*16B
__device__ __forceinline__ void gload_lds16(const bf16* g, bf16* l) {
  __builtin_amdgcn_global_load_lds(
      (const __attribute__((address_space(1))) unsigned int*)g,
      (__attribute__((address_space(3))) unsigned int*)l, 16, 0, 0);
}

// ---- Kernel 0: fp32 -> bf16 conversions + static Vf pad fill.
__global__ __launch_bounds__(256) void cvt_bf16(
    const float* __restrict__ x,  const float* __restrict__ wq,
    const float* __restrict__ wk, const float* __restrict__ wv,
    const float* __restrict__ wo,
    bf16* __restrict__ xb, bf16* __restrict__ wqkvb, bf16* __restrict__ wob,
    bf16* __restrict__ vfp)
{
  const int job = blockIdx.y;
  if (job == 5) {
    for (int u = blockIdx.x * 256 + threadIdx.x; u < 64 * 128 * 32;
         u += gridDim.x * 256) {
      const int m5i = u & 15, hb = (u >> 4) & 1, n4 = (u >> 5) & 127,
                bh = u >> 12;
      const short fill = (m5i == 0) ? (short)0x3F80 : (short)0;
      const bf16x8 o = {fill, fill, fill, fill, fill, fill, fill, fill};
      *(bf16x8*)(vfp + (size_t)bh * 131072 + n4 * 1024 + 512 + hb * 256 +
                 (16 + m5i) * 8) = o;
    }
    return;
  }
  const float* src; bf16* dst; int n;
  if (job == 0)      { src = x;  dst = xb;              n = B_ * N_ * C_; }
  else if (job == 1) { src = wq; dst = wqkvb;           n = C_ * C_; }
  else if (job == 2) { src = wk; dst = wqkvb + C_ * C_; n = C_ * C_; }
  else if (job == 3) { src = wv; dst = wqkvb + 2 * C_ * C_; n = C_ * C_; }
  else               { src = wo; dst = wob;             n = C_ * C_; }
  const int stride = gridDim.x * 256 * 8;
  for (int i = (blockIdx.x * 256 + threadIdx.x) * 8; i < n; i += stride)
    *(uint4*)(dst + i) = ld8f_cvt(src + i);
}

// ---- Kernel 1: fused QKV GEMM, m97-style, XCD-chunked block swizzle.
// Q/K blocks use SWAPPED MFMA operands -> 8B vector epilogue stores.
//  Q/K(n,d): slab + (n>>5)*1536 + (d>>4)*512 + ((d>>3)&1)*256 + (n&31)*8 + (d&7)
//  Vf (n,d): slabV + (n>>4)*1024 + (d>>5)*512 + ((n>>3)&1)*256 + (d&31)*8 + (n&7)
__global__ __launch_bounds__(256) void gemm_qkv(
    const bf16* __restrict__ A, const bf16* __restrict__ Bw,
    const float* __restrict__ bq, const float* __restrict__ bk,
    const float* __restrict__ bv,
    bf16* __restrict__ Q, bf16* __restrict__ K, bf16* __restrict__ Vf)
{
  __shared__ __align__(16) bf16 As[128 * 64];
  __shared__ __align__(16) bf16 Bs[128 * 64];

  // XCD-chunked swizzle: nwg=1152=8*144. XCD k (= lid%8) processes 144
  // consecutive tiles = 8 full row-panels x 18 cols -> A 1.6MB + B 3.5MB / L2.
  const int lid  = blockIdx.x + 18 * blockIdx.y;
  const int nlid = (lid & 7) * 144 + (lid >> 3);
  const int bx = nlid % 18, by = nlid / 18;

  const int tid  = threadIdx.x;
  const int lane = tid & 63, wid = tid >> 6;
  const int wm = (wid >> 1) * 64, wn = (wid & 1) * 64;
  const int row0 = by * 128, col0 = bx * 128;
  const int mb = lane & 15, g4 = lane >> 4;
  const int srow = lane >> 3;                    // staging row-in-8
  const int schunk = (lane & 7) ^ (srow & 7);    // swizzled glb k-chunk
  const int z = bx / 6;                          // 768/128=6 blocks per proj

  f32x4 acc[4][4];
#pragma unroll
  for (int i = 0; i < 4; ++i)
#pragma unroll
    for (int j = 0; j < 4; ++j) acc[i][j] = (f32x4){0.f, 0.f, 0.f, 0.f};

  auto kloop = [&](bool swapped) {
    for (int k0 = 0; k0 < C_; k0 += 64) {
#pragma unroll
      for (int t = 0; t < 4; ++t) {
        const int rt = wid * 32 + t * 8;
        gload_lds16(A  + (size_t)(row0 + rt + srow) * C_ + k0 + schunk * 8,
                    As + rt * 64);
        gload_lds16(Bw + (size_t)(col0 + rt + srow) * C_ + k0 + schunk * 8,
                    Bs + rt * 64);
      }
      __syncthreads();
#pragma unroll
      for (int ks = 0; ks < 2; ++ks) {
        const int kchunk = ks * 4 + g4;
        bf16x8 af[4], bfr[4];
#pragma unroll
        for (int i = 0; i < 4; ++i) {
          const int row = wm + i * 16 + mb;
          af[i] = *(const bf16x8*)(As + row * 64 + (kchunk ^ (row & 7)) * 8);
        }
#pragma unroll
        for (int j = 0; j < 4; ++j) {
          const int col = wn + j * 16 + mb;
          bfr[j] = *(const bf16x8*)(Bs + col * 64 + (kchunk ^ (col & 7)) * 8);
        }
        if (swapped) {
#pragma unroll
          for (int i = 0; i < 4; ++i)
#pragma unroll
            for (int j = 0; j < 4; ++j)
              acc[i][j] = __builtin_amdgcn_mfma_f32_16x16x32_bf16(bfr[j], af[i], acc[i][j], 0, 0, 0);
        } else {
#pragma unroll
          for (int i = 0; i < 4; ++i)
#pragma unroll
            for (int j = 0; j < 4; ++j)
              acc[i][j] = __builtin_amdgcn_mfma_f32_16x16x32_bf16(af[i], bfr[j], acc[i][j], 0, 0, 0);
        }
      }
      __syncthreads();
    }
  };

  const int b_ = row0 >> 11;
  const int nb = (row0 & (N_ - 1)) + wm;         // local-n base of this wave
  if (z < 2) {                                   // ---- Q or K (swapped D^T)
    kloop(true);
    const float* bias = (z == 0) ? bq : bk;
    bf16* dst = (z == 0) ? Q : K;
    const float sc = (z == 0) ? (SCALE_ * LOG2E_) : 1.0f;
    // D^T: col(lane&15)=n-side (af), row(g4*4+reg)=feature-side (bfr)
#pragma unroll
    for (int j = 0; j < 4; ++j) {
      const int c = col0 - z * 768 + wn + j * 16 + g4 * 4;  // 4 consecutive feats
      const int h = c / D_, d0 = c % D_;          // 4|48: no head crossing
      const float4 bb = *(const float4*)(bias + c);
      bf16* slabp = dst + (size_t)(b_ * H_ + h) * (N_ * D_);
      const int dpart = (d0 >> 4) * 512 + ((d0 >> 3) & 1) * 256 + (d0 & 7);
#pragma unroll
      for (int i = 0; i < 4; ++i) {
        const int n = nb + i * 16 + mb;
        u32x2 wv;
        wv.x = pk2((acc[i][j][0] + bb.x) * sc, (acc[i][j][1] + bb.y) * sc);
        wv.y = pk2((acc[i][j][2] + bb.z) * sc, (acc[i][j][3] + bb.w) * sc);
        *(u32x2*)(slabp + (n >> 5) * 1536 + dpart + (n & 31) * 8) = wv;
      }
    }
  } else {                                       // ---- V -> Vf (orig order)
    kloop(false);
#pragma unroll
    for (int j = 0; j < 4; ++j) {
      const int oo = col0 - 2 * 768 + wn + j * 16 + mb;
      const int h = oo / D_, d = oo % D_;
      const float bb = bv[oo];
      bf16* slabp = Vf + (size_t)(b_ * H_ + h) * (N_ * 64);
      const int dpart = (d >> 5) * 512 + ((g4 >> 1) * 32 + (d & 31)) * 8 +
                        (g4 & 1) * 4;
#pragma unroll
      for (int i = 0; i < 4; ++i) {
        u32x2 wv;
        wv.x = pk2(acc[i][j][0] + bb, acc[i][j][1] + bb);
        wv.y = pk2(acc[i][j][2] + bb, acc[i][j][3] + bb);
        *(u32x2*)(slabp + ((nb >> 4) + i) * 1024 + dpart) = wv;
      }
    }
  }
}

// ---- Kernel 2: LDS-staged register flash attention, QBLK=64 per wave.
// Sequential A/B halves (round-6 proven; interleave attempts get
// re-serialized by the register allocator — measured R2/R8).
__global__ __launch_bounds__(256, 2) void attn_mfma(
    const bf16* __restrict__ Qf, const bf16* __restrict__ Kf,
    const bf16* __restrict__ Vf, const float* __restrict__ x,
    bf16* __restrict__ Yb)
{
  __shared__ __align__(16) bf16 Ls[2 * 7168];    // 2 bufs x (6KB K + 8KB V)

  const int tid  = threadIdx.x;
  const int lane = tid & 63, wid = tid >> 6;
  const int m5 = lane & 31, hi = lane >> 5;
  const int bh = blockIdx.x;
  const int b_ = bh >> 4, h = bh & 15;
  const int q0 = blockIdx.y * 256 + wid * 64;    // 64 q rows per wave
  const size_t slab  = (size_t)bh * (N_ * D_);
  const size_t slabV = (size_t)bh * (N_ * 64);

  bf16x8 qfA[3], qfB[3];
  const int kgq = q0 >> 5;
#pragma unroll
  for (int kc = 0; kc < 3; ++kc) {
    qfA[kc] = *(const bf16x8*)(Qf + slab + (size_t)(((kgq * 3 + kc) * 64) + lane) * 8);
    qfB[kc] = *(const bf16x8*)(Qf + slab + (size_t)((((kgq + 1) * 3 + kc) * 64) + lane) * 8);
  }

  f32x16 zf;
#pragma unroll
  for (int r = 0; r < 16; ++r) zf[r] = 0.f;

  f32x16 OA[2], OB[2];
#pragma unroll
  for (int dt = 0; dt < 2; ++dt)
#pragma unroll
    for (int r = 0; r < 16; ++r) { OA[dt][r] = 0.f; OB[dt][r] = 0.f; }

  const bf16* kb = Kf + slab  + (size_t)lane * 8;
  const bf16* vb = Vf + slabV + (size_t)lane * 8;
  auto stage = [&](int t, int buf) {
    bf16* dstb = Ls + buf * 7168;
    const bf16* kt = kb + (size_t)t * 3072;
    const bf16* vt = vb + (size_t)t * 4096;
    for (int c = wid; c < 14; c += 4) {
      if (c < 6) gload_lds16(kt + c * 512, dstb + c * 512);
      else       gload_lds16(vt + (c - 6) * 512, dstb + c * 512);
    }
  };

  auto smpv = [&](f32x16& S, f32x16& O0, f32x16& O1, bf16x8 (&vA)[2][2]) {
#pragma unroll
    for (int r = 0; r < 16; ++r)
      S[r] = __builtin_amdgcn_exp2f(S[r]);
#pragma unroll
    for (int ks = 0; ks < 2; ++ks) {
      const int qa = ks * 2;
      const unsigned A0 = pk2(S[4 * qa + 0], S[4 * qa + 1]);
      const unsigned A1 = pk2(S[4 * qa + 2], S[4 * qa + 3]);
      const unsigned B0 = pk2(S[4 * qa + 4], S[4 * qa + 5]);
      const unsigned B1 = pk2(S[4 * qa + 6], S[4 * qa + 7]);
      const u32x2 r02 = __builtin_amdgcn_permlane32_swap(A0, B0, false, false);
      const u32x2 r13 = __builtin_amdgcn_permlane32_swap(A1, B1, false, false);
      u32x4 pw;
      pw.x = r02.x; pw.y = r13.x; pw.z = r02.y; pw.w = r13.y;
      const bf16x8 pb = (bf16x8)pw;
      O0 = __builtin_amdgcn_mfma_f32_32x32x16_bf16(vA[ks][0], pb, O0, 0, 0, 0);
      O1 = __builtin_amdgcn_mfma_f32_32x32x16_bf16(vA[ks][1], pb, O1, 0, 0, 0);
    }
  };

  auto sub = [&](int buf, int s) {
    const bf16* Lb = Ls + buf * 7168 + (size_t)lane * 8;
    bf16x8 kf[3], vA[2][2];
#pragma unroll
    for (int kc = 0; kc < 3; ++kc)
      kf[kc] = *(const bf16x8*)(Lb + (s * 3 + kc) * 512);
#pragma unroll
    for (int ks = 0; ks < 2; ++ks)
#pragma unroll
      for (int dt = 0; dt < 2; ++dt)
        vA[ks][dt] = *(const bf16x8*)(Lb + (6 + s * 4 + ks * 2 + dt) * 512);
    {
      f32x16 S;
      S = __builtin_amdgcn_mfma_f32_32x32x16_bf16(kf[0], qfA[0], zf, 0, 0, 0);
      S = __builtin_amdgcn_mfma_f32_32x32x16_bf16(kf[1], qfA[1], S, 0, 0, 0);
      S = __builtin_amdgcn_mfma_f32_32x32x16_bf16(kf[2], qfA[2], S, 0, 0, 0);
      smpv(S, OA[0], OA[1], vA);
    }
    {
      f32x16 S;
      S = __builtin_amdgcn_mfma_f32_32x32x16_bf16(kf[0], qfB[0], zf, 0, 0, 0);
      S = __builtin_amdgcn_mfma_f32_32x32x16_bf16(kf[1], qfB[1], S, 0, 0, 0);
      S = __builtin_amdgcn_mfma_f32_32x32x16_bf16(kf[2], qfB[2], S, 0, 0, 0);
      smpv(S, OB[0], OB[1], vA);
    }
  };

  stage(0, 0);
  __syncthreads();
  int buf = 0;
#pragma unroll 1
  for (int t = 0; t < 32; ++t) {
    if (t + 1 < 32) stage(t + 1, buf ^ 1);     // prefetch next tile first
    sub(buf, 0);
    sub(buf, 1);
    __syncthreads();                           // drains vmcnt: next buf ready
    buf ^= 1;
  }

  auto epi = [&](const f32x16& O0, const f32x16& O1, int qbase) {
    const float lf = O1[8];
    const unsigned lu = __builtin_bit_cast(unsigned, lf);
    const u32x2 lsw = __builtin_amdgcn_permlane32_swap(lu, lu, false, false);
    const float Lv = __builtin_bit_cast(float, lsw.x);
    const float inv = 1.f / Lv;
    const int n = qbase + m5;
    const size_t rowoff = ((size_t)(b_ * N_ + n)) * C_ + h * D_;
#pragma unroll
    for (int qq = 0; qq < 4; ++qq) {
      const size_t off = rowoff + 8 * qq + 4 * hi;      // d = 8qq+4hi .. +3
      const float4 xr = *(const float4*)(x + off);
      u32x2 wv;
      wv.x = pk2(O0[4 * qq + 0] * inv + xr.x, O0[4 * qq + 1] * inv + xr.y);
      wv.y = pk2(O0[4 * qq + 2] * inv + xr.z, O0[4 * qq + 3] * inv + xr.w);
      *(u32x2*)(Yb + off) = wv;
    }
#pragma unroll
    for (int qq = 0; qq < 2; ++qq) {
      const size_t off = rowoff + 32 + 8 * qq + 4 * hi; // d = 32+8qq+4hi .. +3
      const float4 xr = *(const float4*)(x + off);
      u32x2 wv;
      wv.x = pk2(O1[4 * qq + 0] * inv + xr.x, O1[4 * qq + 1] * inv + xr.y);
      wv.y = pk2(O1[4 * qq + 2] * inv + xr.z, O1[4 * qq + 3] * inv + xr.w);
      *(u32x2*)(Yb + off) = wv;
    }
  };
  epi(OA[0], OA[1], q0);
  epi(OB[0], OB[1], q0 + 32);
}

// ---- Kernel 3: O projection + residuals. 64x128 tile -> 768 blocks
// (3 blocks/CU: restores cross-block barrier-stall hiding; was 1.5/CU).
// Swapped MFMA: thread owns 4 consecutive o at fixed r -> float4 stores.
// out[r][o] = acc + bo[o] + float(Yb[r][o]) + x[r][o]
__global__ __launch_bounds__(256) void gemm_out(
    const bf16* __restrict__ Yb, const bf16* __restrict__ Bw,
    const float* __restrict__ bo, const float* __restrict__ x,
    float* __restrict__ out)
{
  __shared__ __align__(16) bf16 As[64 * 64];     // 8 KB
  __shared__ __align__(16) bf16 Bs[128 * 64];    // 16 KB

  // XCD-chunked swizzle: nwg=768=8*96 -> per XCD: 16 row-panels x 6 cols.
  const int lid  = blockIdx.x + 6 * blockIdx.y;
  const int nlid = (lid & 7) * 96 + (lid >> 3);
  const int bx = nlid % 6, by = nlid / 6;

  const int tid  = threadIdx.x;
  const int lane = tid & 63, wid = tid >> 6;
  const int wm = (wid >> 1) * 32, wn = (wid & 1) * 64;
  const int row0 = by * 64, col0 = bx * 128;
  const int mb = lane & 15, g4 = lane >> 4;
  const int srow = lane >> 3;
  const int schunk = (lane & 7) ^ (srow & 7);

  f32x4 acc[2][4];
#pragma unroll
  for (int i = 0; i < 2; ++i)
#pragma unroll
    for (int j = 0; j < 4; ++j) acc[i][j] = (f32x4){0.f, 0.f, 0.f, 0.f};

  for (int k0 = 0; k0 < C_; k0 += 64) {
#pragma unroll
    for (int t = 0; t < 2; ++t) {               // A: 64 rows = 4 waves x 16
      const int rt = wid * 16 + t * 8;
      gload_lds16(Yb + (size_t)(row0 + rt + srow) * C_ + k0 + schunk * 8,
                  As + rt * 64);
    }
#pragma unroll
    for (int t = 0; t < 4; ++t) {               // B: 128 rows = 4 waves x 32
      const int rt = wid * 32 + t * 8;
      gload_lds16(Bw + (size_t)(col0 + rt + srow) * C_ + k0 + schunk * 8,
                  Bs + rt * 64);
    }
    __syncthreads();
#pragma unroll
    for (int ks = 0; ks < 2; ++ks) {
      const int kchunk = ks * 4 + g4;
      bf16x8 af[2], bfr[4];
#pragma unroll
      for (int i = 0; i < 2; ++i) {
        const int row = wm + i * 16 + mb;
        af[i] = *(const bf16x8*)(As + row * 64 + (kchunk ^ (row & 7)) * 8);
      }
#pragma unroll
      for (int j = 0; j < 4; ++j) {
        const int col = wn + j * 16 + mb;
        bfr[j] = *(const bf16x8*)(Bs + col * 64 + (kchunk ^ (col & 7)) * 8);
      }
#pragma unroll
      for (int i = 0; i < 2; ++i)
#pragma unroll
        for (int j = 0; j < 4; ++j)
          acc[i][j] = __builtin_amdgcn_mfma_f32_16x16x32_bf16(bfr[j], af[i], acc[i][j], 0, 0, 0);
    }
    __syncthreads();
  }

  // D^T: col(lane&15)=r-side (af rows), row(g4*4+reg)=o-side (bfr rows)
#pragma unroll
  for (int j = 0; j < 4; ++j) {
    const int o0 = col0 + wn + j * 16 + g4 * 4;
    const float4 bb = *(const float4*)(bo + o0);
#pragma unroll
    for (int i = 0; i < 2; ++i) {
      const int r = row0 + wm + i * 16 + mb;
      const size_t off = (size_t)r * C_ + o0;
      const u32x2 yv = *(const u32x2*)(Yb + off);   // 4 bf16
      const float4 xr = *(const float4*)(x + off);
      float4 ov;
      ov.x = acc[i][j][0] + bb.x + b2f((unsigned short)(yv.x & 0xffff)) + xr.x;
      ov.y = acc[i][j][1] + bb.y + b2f((unsigned short)(yv.x >> 16))    + xr.y;
      ov.z = acc[i][j][2] + bb.z + b2f((unsigned short)(yv.y & 0xffff)) + xr.z;
      ov.w = acc[i][j][3] + bb.w + b2f((unsigned short)(yv.y >> 16))    + xr.w;
      *(float4*)(out + off) = ov;
    }
  }
}

extern "C" void kernel_launch(void* const* d_in, const int* in_sizes, int n_in,
                              void* d_out, int out_size, void* d_ws, size_t ws_size,
                              hipStream_t stream)
{
  const float* x  = (const float*)d_in[0];
  const float* wq = (const float*)d_in[1];
  const float* bq = (const float*)d_in[2];
  const float* wk = (const float*)d_in[3];
  const float* bk = (const float*)d_in[4];
  const float* wv = (const float*)d_in[5];
  const float* bv = (const float*)d_in[6];
  const float* wo = (const float*)d_in[7];
  const float* bo = (const float*)d_in[8];
  float* out = (float*)d_out;

  const size_t nEl  = (size_t)B_ * N_ * C_;      // 6,291,456
  const size_t wEl  = (size_t)C_ * C_;           // 589,824
  const size_t vfEl = (size_t)B_ * H_ * N_ * 64; // 8,388,608 (padded V frags)
  bf16* Q     = (bf16*)d_ws;                     // fragment layouts
  bf16* K     = Q + nEl;
  bf16* Vf    = K + nEl;                         // padded V A-fragment layout
  bf16* Yb    = Vf + vfEl;                       // y = attn+x, bf16
  bf16* xb    = Yb + nEl;                        // [8192][768] bf16
  bf16* wqkvb = xb + nEl;                        // [2304][768] bf16 stacked
  bf16* wob   = wqkvb + 3 * wEl;                 // [768][768] bf16

  dim3 gcvt(768, 6);                             // job 5 = Vf pad fill
  cvt_bf16<<<gcvt, dim3(256), 0, stream>>>(x, wq, wk, wv, wo, xb, wqkvb, wob, Vf);

  dim3 gqkv(18, 64);                             // 2304/128 x 8192/128
  gemm_qkv<<<gqkv, dim3(256), 0, stream>>>(xb, wqkvb, bq, bk, bv, Q, K, Vf);

  dim3 gattn(B_ * H_, N_ / 256);                 // (64, 8), QBLK=64/wave
  attn_mfma<<<gattn, dim3(256), 0, stream>>>(Q, K, Vf, x, Yb);

  dim3 gout(6, 128);                             // 768/128 x 8192/64
  gemm_out<<<gout, dim3(256), 0, stream>>>(Yb, wob, bo, x, out);
}

// Round 10
// 224.285 us; speedup vs baseline: 1.1681x; 1.0032x over previous
//
#include <hip/hip_runtime.h>
#include <hip/hip_bf16.h>

// B=4, N=2048, C=768, H=16, D=48. FP32 in/out.
// Pipeline: cvt(x,W->bf16, Vf-pad) -> gemm_qkv (fused, XCD-swizzled, swapped-
//           operand MFMA for Q/K; direct fragment layouts) -> attn (LDS-staged
//           K/V, QBLK=32/wave, 4 blocks/CU, setprio MFMA, bf16 residual) ->
//           gemm_out (64x128 tile, XCD-swizzled, swapped-operand MFMA).
#define B_ 4
#define N_ 2048
#define C_ 768
#define H_ 16
#define D_ 48
#define SCALE_ 0.14433756729740643f
#define LOG2E_ 1.44269504088896f

using bf16 = __hip_bfloat16;
using bf16x8 = __attribute__((ext_vector_type(8))) short;
using f32x4  = __attribute__((ext_vector_type(4))) float;
using f32x16 = __attribute__((ext_vector_type(16))) float;
using u32x2  = __attribute__((ext_vector_type(2))) unsigned int;
using u32x4  = __attribute__((ext_vector_type(4))) unsigned int;

__device__ __forceinline__ unsigned short f2b(float f) {
  bf16 h = __float2bfloat16(f);
  return *reinterpret_cast<unsigned short*>(&h);
}
__device__ __forceinline__ unsigned int pack2(float lo, float hi) {
  return (unsigned int)f2b(lo) | ((unsigned int)f2b(hi) << 16);
}
// packed f32->bf16 (RNE), single instruction
__device__ __forceinline__ unsigned int pk2(float lo, float hi) {
  unsigned int r;
  asm("v_cvt_pk_bf16_f32 %0, %1, %2" : "=v"(r) : "v"(lo), "v"(hi));
  return r;
}
// bf16 (as u16) -> f32 exact
__device__ __forceinline__ float b2f(unsigned short us) {
  return __builtin_bit_cast(float, (unsigned)us << 16);
}
__device__ __forceinline__ uint4 ld8f_cvt(const float* p) {
  float4 a = *reinterpret_cast<const float4*>(p);
  float4 b = *reinterpret_cast<const float4*>(p + 4);
  uint4 u;
  u.x = pack2(a.x, a.y); u.y = pack2(a.z, a.w);
  u.z = pack2(b.x, b.y); u.w = pack2(b.z, b.w);
  return u;
}
// async global->LDS, 16B per lane; LDS dest = wave-uniform base + lane*16B
__device__ __forceinline__ void gload_lds16(const bf16* g, bf16* l) {
  __builtin_amdgcn_global_load_lds(
      (const __attribute__((address_space(1))) unsigned int*)g,
      (__attribute__((address_space(3))) unsigned int*)l, 16, 0, 0);
}

// ---- Kernel 0: fp32 -> bf16 conversions + static Vf pad fill.
__global__ __launch_bounds__(256) void cvt_bf16(
    const float* __restrict__ x,  const float* __restrict__ wq,
    const float* __restrict__ wk, const float* __restrict__ wv,
    const float* __restrict__ wo,
    bf16* __restrict__ xb, bf16* __restrict__ wqkvb, bf16* __restrict__ wob,
    bf16* __restrict__ vfp)
{
  const int job = blockIdx.y;
  if (job == 5) {
    for (int u = blockIdx.x * 256 + threadIdx.x; u < 64 * 128 * 32;
         u += gridDim.x * 256) {
      const int m5i = u & 15, hb = (u >> 4) & 1, n4 = (u >> 5) & 127,
                bh = u >> 12;
      const short fill = (m5i == 0) ? (short)0x3F80 : (short)0;
      const bf16x8 o = {fill, fill, fill, fill, fill, fill, fill, fill};
      *(bf16x8*)(vfp + (size_t)bh * 131072 + n4 * 1024 + 512 + hb * 256 +
                 (16 + m5i) * 8) = o;
    }
    return;
  }
  const float* src; bf16* dst; int n;
  if (job == 0)      { src = x;  dst = xb;              n = B_ * N_ * C_; }
  else if (job == 1) { src = wq; dst = wqkvb;           n = C_ * C_; }
  else if (job == 2) { src = wk; dst = wqkvb + C_ * C_; n = C_ * C_; }
  else if (job == 3) { src = wv; dst = wqkvb + 2 * C_ * C_; n = C_ * C_; }
  else               { src = wo; dst = wob;             n = C_ * C_; }
  const int stride = gridDim.x * 256 * 8;
  for (int i = (blockIdx.x * 256 + threadIdx.x) * 8; i < n; i += stride)
    *(uint4*)(dst + i) = ld8f_cvt(src + i);
}

// ---- Kernel 1: fused QKV GEMM, m97-style, XCD-chunked block swizzle.
// Q/K blocks use SWAPPED MFMA operands -> 8B vector epilogue stores.
//  Q/K(n,d): slab + (n>>5)*1536 + (d>>4)*512 + ((d>>3)&1)*256 + (n&31)*8 + (d&7)
//  Vf (n,d): slabV + (n>>4)*1024 + (d>>5)*512 + ((n>>3)&1)*256 + (d&31)*8 + (n&7)
__global__ __launch_bounds__(256) void gemm_qkv(
    const bf16* __restrict__ A, const bf16* __restrict__ Bw,
    const float* __restrict__ bq, const float* __restrict__ bk,
    const float* __restrict__ bv,
    bf16* __restrict__ Q, bf16* __restrict__ K, bf16* __restrict__ Vf)
{
  __shared__ __align__(16) bf16 As[128 * 64];
  __shared__ __align__(16) bf16 Bs[128 * 64];

  // XCD-chunked swizzle: nwg=1152=8*144. XCD k (= lid%8) processes 144
  // consecutive tiles = 8 full row-panels x 18 cols -> A 1.6MB + B 3.5MB / L2.
  const int lid  = blockIdx.x + 18 * blockIdx.y;
  const int nlid = (lid & 7) * 144 + (lid >> 3);
  const int bx = nlid % 18, by = nlid / 18;

  const int tid  = threadIdx.x;
  const int lane = tid & 63, wid = tid >> 6;
  const int wm = (wid >> 1) * 64, wn = (wid & 1) * 64;
  const int row0 = by * 128, col0 = bx * 128;
  const int mb = lane & 15, g4 = lane >> 4;
  const int srow = lane >> 3;                    // staging row-in-8
  const int schunk = (lane & 7) ^ (srow & 7);    // swizzled glb k-chunk
  const int z = bx / 6;                          // 768/128=6 blocks per proj

  f32x4 acc[4][4];
#pragma unroll
  for (int i = 0; i < 4; ++i)
#pragma unroll
    for (int j = 0; j < 4; ++j) acc[i][j] = (f32x4){0.f, 0.f, 0.f, 0.f};

  auto kloop = [&](bool swapped) {
    for (int k0 = 0; k0 < C_; k0 += 64) {
#pragma unroll
      for (int t = 0; t < 4; ++t) {
        const int rt = wid * 32 + t * 8;
        gload_lds16(A  + (size_t)(row0 + rt + srow) * C_ + k0 + schunk * 8,
                    As + rt * 64);
        gload_lds16(Bw + (size_t)(col0 + rt + srow) * C_ + k0 + schunk * 8,
                    Bs + rt * 64);
      }
      __syncthreads();
#pragma unroll
      for (int ks = 0; ks < 2; ++ks) {
        const int kchunk = ks * 4 + g4;
        bf16x8 af[4], bfr[4];
#pragma unroll
        for (int i = 0; i < 4; ++i) {
          const int row = wm + i * 16 + mb;
          af[i] = *(const bf16x8*)(As + row * 64 + (kchunk ^ (row & 7)) * 8);
        }
#pragma unroll
        for (int j = 0; j < 4; ++j) {
          const int col = wn + j * 16 + mb;
          bfr[j] = *(const bf16x8*)(Bs + col * 64 + (kchunk ^ (col & 7)) * 8);
        }
        if (swapped) {
#pragma unroll
          for (int i = 0; i < 4; ++i)
#pragma unroll
            for (int j = 0; j < 4; ++j)
              acc[i][j] = __builtin_amdgcn_mfma_f32_16x16x32_bf16(bfr[j], af[i], acc[i][j], 0, 0, 0);
        } else {
#pragma unroll
          for (int i = 0; i < 4; ++i)
#pragma unroll
            for (int j = 0; j < 4; ++j)
              acc[i][j] = __builtin_amdgcn_mfma_f32_16x16x32_bf16(af[i], bfr[j], acc[i][j], 0, 0, 0);
        }
      }
      __syncthreads();
    }
  };

  const int b_ = row0 >> 11;
  const int nb = (row0 & (N_ - 1)) + wm;         // local-n base of this wave
  if (z < 2) {                                   // ---- Q or K (swapped D^T)
    kloop(true);
    const float* bias = (z == 0) ? bq : bk;
    bf16* dst = (z == 0) ? Q : K;
    const float sc = (z == 0) ? (SCALE_ * LOG2E_) : 1.0f;
    // D^T: col(lane&15)=n-side (af), row(g4*4+reg)=feature-side (bfr)
#pragma unroll
    for (int j = 0; j < 4; ++j) {
      const int c = col0 - z * 768 + wn + j * 16 + g4 * 4;  // 4 consecutive feats
      const int h = c / D_, d0 = c % D_;          // 4|48: no head crossing
      const float4 bb = *(const float4*)(bias + c);
      bf16* slabp = dst + (size_t)(b_ * H_ + h) * (N_ * D_);
      const int dpart = (d0 >> 4) * 512 + ((d0 >> 3) & 1) * 256 + (d0 & 7);
#pragma unroll
      for (int i = 0; i < 4; ++i) {
        const int n = nb + i * 16 + mb;
        u32x2 wv;
        wv.x = pk2((acc[i][j][0] + bb.x) * sc, (acc[i][j][1] + bb.y) * sc);
        wv.y = pk2((acc[i][j][2] + bb.z) * sc, (acc[i][j][3] + bb.w) * sc);
        *(u32x2*)(slabp + (n >> 5) * 1536 + dpart + (n & 31) * 8) = wv;
      }
    }
  } else {                                       // ---- V -> Vf (orig order)
    kloop(false);
#pragma unroll
    for (int j = 0; j < 4; ++j) {
      const int oo = col0 - 2 * 768 + wn + j * 16 + mb;
      const int h = oo / D_, d = oo % D_;
      const float bb = bv[oo];
      bf16* slabp = Vf + (size_t)(b_ * H_ + h) * (N_ * 64);
      const int dpart = (d >> 5) * 512 + ((g4 >> 1) * 32 + (d & 31)) * 8 +
                        (g4 & 1) * 4;
#pragma unroll
      for (int i = 0; i < 4; ++i) {
        u32x2 wv;
        wv.x = pk2(acc[i][j][0] + bb, acc[i][j][1] + bb);
        wv.y = pk2(acc[i][j][2] + bb, acc[i][j][3] + bb);
        *(u32x2*)(slabp + ((nb >> 4) + i) * 1024 + dpart) = wv;
      }
    }
  }
}

// ---- Kernel 2: LDS-staged register flash attention (R5-proven structure:
// QBLK=32/wave, 4 blocks/CU). Adds: s_setprio(1) around MFMA clusters (T5 —
// blocks on one CU run at different phases, so MFMA waves win arbitration),
// and bf16 residual read from xb (halves residual HBM + load count).
__global__ __launch_bounds__(256, 4) void attn_mfma(
    const bf16* __restrict__ Qf, const bf16* __restrict__ Kf,
    const bf16* __restrict__ Vf, const bf16* __restrict__ xb,
    bf16* __restrict__ Yb)
{
  __shared__ __align__(16) bf16 Ls[2 * 7168];    // 2 bufs x (6KB K + 8KB V)

  const int tid  = threadIdx.x;
  const int lane = tid & 63, wid = tid >> 6;
  const int m5 = lane & 31, hi = lane >> 5;
  const int bh = blockIdx.x;
  const int b_ = bh >> 4, h = bh & 15;
  const int q0 = blockIdx.y * 128 + wid * 32;
  const size_t slab  = (size_t)bh * (N_ * D_);
  const size_t slabV = (size_t)bh * (N_ * 64);

  // Q fragments (32 q rows x 48 d), live whole kernel
  bf16x8 qf[3];
  const int kgq = q0 >> 5;
#pragma unroll
  for (int kc = 0; kc < 3; ++kc)
    qf[kc] = *(const bf16x8*)(Qf + slab + (size_t)(((kgq * 3 + kc) * 64) + lane) * 8);

  f32x16 zf;
#pragma unroll
  for (int r = 0; r < 16; ++r) zf[r] = 0.f;

  f32x16 Oacc[2];
#pragma unroll
  for (int dt = 0; dt < 2; ++dt)
#pragma unroll
    for (int r = 0; r < 16; ++r) Oacc[dt][r] = 0.f;

  // stage tile t (64 keys) into buffer buf: chunks 0-5 = K (6KB), 6-13 = V (8KB)
  const bf16* kb = Kf + slab  + (size_t)lane * 8;
  const bf16* vb = Vf + slabV + (size_t)lane * 8;
  auto stage = [&](int t, int buf) {
    bf16* dstb = Ls + buf * 7168;
    const bf16* kt = kb + (size_t)t * 3072;
    const bf16* vt = vb + (size_t)t * 4096;
    for (int c = wid; c < 14; c += 4) {
      if (c < 6) gload_lds16(kt + c * 512, dstb + c * 512);
      else       gload_lds16(vt + (c - 6) * 512, dstb + c * 512);
    }
  };

  // compute one 32-key sub-tile from LDS buffer buf
  auto sub = [&](int buf, int s) {
    const bf16* Lb = Ls + buf * 7168 + (size_t)lane * 8;
    bf16x8 kf[3], vA[2][2];
#pragma unroll
    for (int kc = 0; kc < 3; ++kc)
      kf[kc] = *(const bf16x8*)(Lb + (s * 3 + kc) * 512);
#pragma unroll
    for (int ks = 0; ks < 2; ++ks)
#pragma unroll
      for (int dt = 0; dt < 2; ++dt)
        vA[ks][dt] = *(const bf16x8*)(Lb + (6 + s * 4 + ks * 2 + dt) * 512);
    f32x16 S;
    __builtin_amdgcn_s_setprio(1);
    S = __builtin_amdgcn_mfma_f32_32x32x16_bf16(kf[0], qf[0], zf, 0, 0, 0);
    S = __builtin_amdgcn_mfma_f32_32x32x16_bf16(kf[1], qf[1], S, 0, 0, 0);
    S = __builtin_amdgcn_mfma_f32_32x32x16_bf16(kf[2], qf[2], S, 0, 0, 0);
    __builtin_amdgcn_s_setprio(0);
#pragma unroll
    for (int r = 0; r < 16; ++r)
      S[r] = __builtin_amdgcn_exp2f(S[r]);
    // S reg 4*qq+rr = P[q=lane&31][k32 = rr + 8*qq + 4*hi]
#pragma unroll
    for (int ks = 0; ks < 2; ++ks) {
      const int qa = ks * 2;
      const unsigned A0 = pk2(S[4 * qa + 0], S[4 * qa + 1]);
      const unsigned A1 = pk2(S[4 * qa + 2], S[4 * qa + 3]);
      const unsigned B0 = pk2(S[4 * qa + 4], S[4 * qa + 5]);
      const unsigned B1 = pk2(S[4 * qa + 6], S[4 * qa + 7]);
      const u32x2 r02 = __builtin_amdgcn_permlane32_swap(A0, B0, false, false);
      const u32x2 r13 = __builtin_amdgcn_permlane32_swap(A1, B1, false, false);
      u32x4 pw;
      pw.x = r02.x; pw.y = r13.x; pw.z = r02.y; pw.w = r13.y;
      const bf16x8 pb = (bf16x8)pw;
      __builtin_amdgcn_s_setprio(1);
      Oacc[0] = __builtin_amdgcn_mfma_f32_32x32x16_bf16(vA[ks][0], pb, Oacc[0], 0, 0, 0);
      Oacc[1] = __builtin_amdgcn_mfma_f32_32x32x16_bf16(vA[ks][1], pb, Oacc[1], 0, 0, 0);
      __builtin_amdgcn_s_setprio(0);
    }
  };

  stage(0, 0);
  __syncthreads();
  int buf = 0;
#pragma unroll 1
  for (int t = 0; t < 32; ++t) {
    if (t + 1 < 32) stage(t + 1, buf ^ 1);     // prefetch next tile first
    sub(buf, 0);
    sub(buf, 1);
    __syncthreads();                           // drains vmcnt: next buf ready
    buf ^= 1;
  }

  // L[q] lives in Oacc[1] row 16 = reg 8 of hi=0 lanes; broadcast to hi=1.
  const float lf = Oacc[1][8];
  const unsigned lu = __builtin_bit_cast(unsigned, lf);
  const u32x2 lsw = __builtin_amdgcn_permlane32_swap(lu, lu, false, false);
  const float Lv = __builtin_bit_cast(float, lsw.x);
  const float inv = 1.f / Lv;

  const int n = q0 + m5;
  const size_t rowoff = ((size_t)(b_ * N_ + n)) * C_ + h * D_;
#pragma unroll
  for (int qq = 0; qq < 4; ++qq) {
    const size_t off = rowoff + 8 * qq + 4 * hi;      // d = 8qq+4hi .. +3
    const u32x2 xv = *(const u32x2*)(xb + off);       // 4 bf16 residuals
    u32x2 wv;
    wv.x = pk2(Oacc[0][4 * qq + 0] * inv + b2f((unsigned short)(xv.x & 0xffff)),
               Oacc[0][4 * qq + 1] * inv + b2f((unsigned short)(xv.x >> 16)));
    wv.y = pk2(Oacc[0][4 * qq + 2] * inv + b2f((unsigned short)(xv.y & 0xffff)),
               Oacc[0][4 * qq + 3] * inv + b2f((unsigned short)(xv.y >> 16)));
    *(u32x2*)(Yb + off) = wv;
  }
#pragma unroll
  for (int qq = 0; qq < 2; ++qq) {
    const size_t off = rowoff + 32 + 8 * qq + 4 * hi; // d = 32+8qq+4hi .. +3
    const u32x2 xv = *(const u32x2*)(xb + off);
    u32x2 wv;
    wv.x = pk2(Oacc[1][4 * qq + 0] * inv + b2f((unsigned short)(xv.x & 0xffff)),
               Oacc[1][4 * qq + 1] * inv + b2f((unsigned short)(xv.x >> 16)));
    wv.y = pk2(Oacc[1][4 * qq + 2] * inv + b2f((unsigned short)(xv.y & 0xffff)),
               Oacc[1][4 * qq + 3] * inv + b2f((unsigned short)(xv.y >> 16)));
    *(u32x2*)(Yb + off) = wv;
  }
}

// ---- Kernel 3: O projection + residuals. 64x128 tile, XCD-swizzled.
// Swapped MFMA: thread owns 4 consecutive o at fixed r -> float4 stores.
// out[r][o] = acc + bo[o] + float(Yb[r][o]) + x[r][o]
__global__ __launch_bounds__(256) void gemm_out(
    const bf16* __restrict__ Yb, const bf16* __restrict__ Bw,
    const float* __restrict__ bo, const float* __restrict__ x,
    float* __restrict__ out)
{
  __shared__ __align__(16) bf16 As[64 * 64];     // 8 KB
  __shared__ __align__(16) bf16 Bs[128 * 64];    // 16 KB

  // XCD-chunked swizzle: nwg=768=8*96 -> per XCD: 16 row-panels x 6 cols.
  const int lid  = blockIdx.x + 6 * blockIdx.y;
  const int nlid = (lid & 7) * 96 + (lid >> 3);
  const int bx = nlid % 6, by = nlid / 6;

  const int tid  = threadIdx.x;
  const int lane = tid & 63, wid = tid >> 6;
  const int wm = (wid >> 1) * 32, wn = (wid & 1) * 64;
  const int row0 = by * 64, col0 = bx * 128;
  const int mb = lane & 15, g4 = lane >> 4;
  const int srow = lane >> 3;
  const int schunk = (lane & 7) ^ (srow & 7);

  f32x4 acc[2][4];
#pragma unroll
  for (int i = 0; i < 2; ++i)
#pragma unroll
    for (int j = 0; j < 4; ++j) acc[i][j] = (f32x4){0.f, 0.f, 0.f, 0.f};

  for (int k0 = 0; k0 < C_; k0 += 64) {
#pragma unroll
    for (int t = 0; t < 2; ++t) {               // A: 64 rows = 4 waves x 16
      const int rt = wid * 16 + t * 8;
      gload_lds16(Yb + (size_t)(row0 + rt + srow) * C_ + k0 + schunk * 8,
                  As + rt * 64);
    }
#pragma unroll
    for (int t = 0; t < 4; ++t) {               // B: 128 rows = 4 waves x 32
      const int rt = wid * 32 + t * 8;
      gload_lds16(Bw + (size_t)(col0 + rt + srow) * C_ + k0 + schunk * 8,
                  Bs + rt * 64);
    }
    __syncthreads();
#pragma unroll
    for (int ks = 0; ks < 2; ++ks) {
      const int kchunk = ks * 4 + g4;
      bf16x8 af[2], bfr[4];
#pragma unroll
      for (int i = 0; i < 2; ++i) {
        const int row = wm + i * 16 + mb;
        af[i] = *(const bf16x8*)(As + row * 64 + (kchunk ^ (row & 7)) * 8);
      }
#pragma unroll
      for (int j = 0; j < 4; ++j) {
        const int col = wn + j * 16 + mb;
        bfr[j] = *(const bf16x8*)(Bs + col * 64 + (kchunk ^ (col & 7)) * 8);
      }
#pragma unroll
      for (int i = 0; i < 2; ++i)
#pragma unroll
        for (int j = 0; j < 4; ++j)
          acc[i][j] = __builtin_amdgcn_mfma_f32_16x16x32_bf16(bfr[j], af[i], acc[i][j], 0, 0, 0);
    }
    __syncthreads();
  }

  // D^T: col(lane&15)=r-side (af rows), row(g4*4+reg)=o-side (bfr rows)
#pragma unroll
  for (int j = 0; j < 4; ++j) {
    const int o0 = col0 + wn + j * 16 + g4 * 4;
    const float4 bb = *(const float4*)(bo + o0);
#pragma unroll
    for (int i = 0; i < 2; ++i) {
      const int r = row0 + wm + i * 16 + mb;
      const size_t off = (size_t)r * C_ + o0;
      const u32x2 yv = *(const u32x2*)(Yb + off);   // 4 bf16
      const float4 xr = *(const float4*)(x + off);
      float4 ov;
      ov.x = acc[i][j][0] + bb.x + b2f((unsigned short)(yv.x & 0xffff)) + xr.x;
      ov.y = acc[i][j][1] + bb.y + b2f((unsigned short)(yv.x >> 16))    + xr.y;
      ov.z = acc[i][j][2] + bb.z + b2f((unsigned short)(yv.y & 0xffff)) + xr.z;
      ov.w = acc[i][j][3] + bb.w + b2f((unsigned short)(yv.y >> 16))    + xr.w;
      *(float4*)(out + off) = ov;
    }
  }
}

extern "C" void kernel_launch(void* const* d_in, const int* in_sizes, int n_in,
                              void* d_out, int out_size, void* d_ws, size_t ws_size,
                              hipStream_t stream)
{
  const float* x  = (const float*)d_in[0];
  const float* wq = (const float*)d_in[1];
  const float* bq = (const float*)d_in[2];
  const float* wk = (const float*)d_in[3];
  const float* bk = (const float*)d_in[4];
  const float* wv = (const float*)d_in[5];
  const float* bv = (const float*)d_in[6];
  const float* wo = (const float*)d_in[7];
  const float* bo = (const float*)d_in[8];
  float* out = (float*)d_out;

  const size_t nEl  = (size_t)B_ * N_ * C_;      // 6,291,456
  const size_t wEl  = (size_t)C_ * C_;           // 589,824
  const size_t vfEl = (size_t)B_ * H_ * N_ * 64; // 8,388,608 (padded V frags)
  bf16* Q     = (bf16*)d_ws;                     // fragment layouts
  bf16* K     = Q + nEl;
  bf16* Vf    = K + nEl;                         // padded V A-fragment layout
  bf16* Yb    = Vf + vfEl;                       // y = attn+x, bf16
  bf16* xb    = Yb + nEl;                        // [8192][768] bf16
  bf16* wqkvb = xb + nEl;                        // [2304][768] bf16 stacked
  bf16* wob   = wqkvb + 3 * wEl;                 // [768][768] bf16

  dim3 gcvt(768, 6);                             // job 5 = Vf pad fill
  cvt_bf16<<<gcvt, dim3(256), 0, stream>>>(x, wq, wk, wv, wo, xb, wqkvb, wob, Vf);

  dim3 gqkv(18, 64);                             // 2304/128 x 8192/128
  gemm_qkv<<<gqkv, dim3(256), 0, stream>>>(xb, wqkvb, bq, bk, bv, Q, K, Vf);

  dim3 gattn(B_ * H_, N_ / 128);                 // (64, 16), QBLK=32/wave
  attn_mfma<<<gattn, dim3(256), 0, stream>>>(Q, K, Vf, xb, Yb);

  dim3 gout(6, 128);                             // 768/128 x 8192/64
  gemm_out<<<gout, dim3(256), 0, stream>>>(Yb, wob, bo, x, out);
}

// Round 11
// 217.278 us; speedup vs baseline: 1.2058x; 1.0322x over previous
//
#include <hip/hip_runtime.h>
#include <hip/hip_bf16.h>

// B=4, N=2048, C=768, H=16, D=48. FP32 in/out.
// Pipeline: cvt(x,W->bf16, Vf-pad) -> gemm_qkv (fused, XCD-swizzled, swapped-
//           operand MFMA for Q/K; direct fragment layouts) -> attn (512-thread
//           blocks: 8 waves share one LDS K/V tile -> per-CU LDS/L2 staging
//           traffic halved at constant wave count; QBLK=32/wave) ->
//           gemm_out (64x128 tile, XCD-swizzled, swapped-operand MFMA).
#define B_ 4
#define N_ 2048
#define C_ 768
#define H_ 16
#define D_ 48
#define SCALE_ 0.14433756729740643f
#define LOG2E_ 1.44269504088896f

using bf16 = __hip_bfloat16;
using bf16x8 = __attribute__((ext_vector_type(8))) short;
using f32x4  = __attribute__((ext_vector_type(4))) float;
using f32x16 = __attribute__((ext_vector_type(16))) float;
using u32x2  = __attribute__((ext_vector_type(2))) unsigned int;
using u32x4  = __attribute__((ext_vector_type(4))) unsigned int;

__device__ __forceinline__ unsigned short f2b(float f) {
  bf16 h = __float2bfloat16(f);
  return *reinterpret_cast<unsigned short*>(&h);
}
__device__ __forceinline__ unsigned int pack2(float lo, float hi) {
  return (unsigned int)f2b(lo) | ((unsigned int)f2b(hi) << 16);
}
// packed f32->bf16 (RNE), single instruction
__device__ __forceinline__ unsigned int pk2(float lo, float hi) {
  unsigned int r;
  asm("v_cvt_pk_bf16_f32 %0, %1, %2" : "=v"(r) : "v"(lo), "v"(hi));
  return r;
}
// bf16 (as u16) -> f32 exact
__device__ __forceinline__ float b2f(unsigned short us) {
  return __builtin_bit_cast(float, (unsigned)us << 16);
}
__device__ __forceinline__ uint4 ld8f_cvt(const float* p) {
  float4 a = *reinterpret_cast<const float4*>(p);
  float4 b = *reinterpret_cast<const float4*>(p + 4);
  uint4 u;
  u.x = pack2(a.x, a.y); u.y = pack2(a.z, a.w);
  u.z = pack2(b.x, b.y); u.w = pack2(b.z, b.w);
  return u;
}
// async global->LDS, 16B per lane; LDS dest = wave-uniform base + lane*16B
__device__ __forceinline__ void gload_lds16(const bf16* g, bf16* l) {
  __builtin_amdgcn_global_load_lds(
      (const __attribute__((address_space(1))) unsigned int*)g,
      (__attribute__((address_space(3))) unsigned int*)l, 16, 0, 0);
}

// ---- Kernel 0: fp32 -> bf16 conversions + static Vf pad fill.
__global__ __launch_bounds__(256) void cvt_bf16(
    const float* __restrict__ x,  const float* __restrict__ wq,
    const float* __restrict__ wk, const float* __restrict__ wv,
    const float* __restrict__ wo,
    bf16* __restrict__ xb, bf16* __restrict__ wqkvb, bf16* __restrict__ wob,
    bf16* __restrict__ vfp)
{
  const int job = blockIdx.y;
  if (job == 5) {
    for (int u = blockIdx.x * 256 + threadIdx.x; u < 64 * 128 * 32;
         u += gridDim.x * 256) {
      const int m5i = u & 15, hb = (u >> 4) & 1, n4 = (u >> 5) & 127,
                bh = u >> 12;
      const short fill = (m5i == 0) ? (short)0x3F80 : (short)0;
      const bf16x8 o = {fill, fill, fill, fill, fill, fill, fill, fill};
      *(bf16x8*)(vfp + (size_t)bh * 131072 + n4 * 1024 + 512 + hb * 256 +
                 (16 + m5i) * 8) = o;
    }
    return;
  }
  const float* src; bf16* dst; int n;
  if (job == 0)      { src = x;  dst = xb;              n = B_ * N_ * C_; }
  else if (job == 1) { src = wq; dst = wqkvb;           n = C_ * C_; }
  else if (job == 2) { src = wk; dst = wqkvb + C_ * C_; n = C_ * C_; }
  else if (job == 3) { src = wv; dst = wqkvb + 2 * C_ * C_; n = C_ * C_; }
  else               { src = wo; dst = wob;             n = C_ * C_; }
  const int stride = gridDim.x * 256 * 8;
  for (int i = (blockIdx.x * 256 + threadIdx.x) * 8; i < n; i += stride)
    *(uint4*)(dst + i) = ld8f_cvt(src + i);
}

// ---- Kernel 1: fused QKV GEMM, m97-style, XCD-chunked block swizzle.
// Q/K blocks use SWAPPED MFMA operands -> 8B vector epilogue stores.
//  Q/K(n,d): slab + (n>>5)*1536 + (d>>4)*512 + ((d>>3)&1)*256 + (n&31)*8 + (d&7)
//  Vf (n,d): slabV + (n>>4)*1024 + (d>>5)*512 + ((n>>3)&1)*256 + (d&31)*8 + (n&7)
__global__ __launch_bounds__(256) void gemm_qkv(
    const bf16* __restrict__ A, const bf16* __restrict__ Bw,
    const float* __restrict__ bq, const float* __restrict__ bk,
    const float* __restrict__ bv,
    bf16* __restrict__ Q, bf16* __restrict__ K, bf16* __restrict__ Vf)
{
  __shared__ __align__(16) bf16 As[128 * 64];
  __shared__ __align__(16) bf16 Bs[128 * 64];

  // XCD-chunked swizzle: nwg=1152=8*144. XCD k (= lid%8) processes 144
  // consecutive tiles = 8 full row-panels x 18 cols -> A 1.6MB + B 3.5MB / L2.
  const int lid  = blockIdx.x + 18 * blockIdx.y;
  const int nlid = (lid & 7) * 144 + (lid >> 3);
  const int bx = nlid % 18, by = nlid / 18;

  const int tid  = threadIdx.x;
  const int lane = tid & 63, wid = tid >> 6;
  const int wm = (wid >> 1) * 64, wn = (wid & 1) * 64;
  const int row0 = by * 128, col0 = bx * 128;
  const int mb = lane & 15, g4 = lane >> 4;
  const int srow = lane >> 3;                    // staging row-in-8
  const int schunk = (lane & 7) ^ (srow & 7);    // swizzled glb k-chunk
  const int z = bx / 6;                          // 768/128=6 blocks per proj

  f32x4 acc[4][4];
#pragma unroll
  for (int i = 0; i < 4; ++i)
#pragma unroll
    for (int j = 0; j < 4; ++j) acc[i][j] = (f32x4){0.f, 0.f, 0.f, 0.f};

  auto kloop = [&](bool swapped) {
    for (int k0 = 0; k0 < C_; k0 += 64) {
#pragma unroll
      for (int t = 0; t < 4; ++t) {
        const int rt = wid * 32 + t * 8;
        gload_lds16(A  + (size_t)(row0 + rt + srow) * C_ + k0 + schunk * 8,
                    As + rt * 64);
        gload_lds16(Bw + (size_t)(col0 + rt + srow) * C_ + k0 + schunk * 8,
                    Bs + rt * 64);
      }
      __syncthreads();
#pragma unroll
      for (int ks = 0; ks < 2; ++ks) {
        const int kchunk = ks * 4 + g4;
        bf16x8 af[4], bfr[4];
#pragma unroll
        for (int i = 0; i < 4; ++i) {
          const int row = wm + i * 16 + mb;
          af[i] = *(const bf16x8*)(As + row * 64 + (kchunk ^ (row & 7)) * 8);
        }
#pragma unroll
        for (int j = 0; j < 4; ++j) {
          const int col = wn + j * 16 + mb;
          bfr[j] = *(const bf16x8*)(Bs + col * 64 + (kchunk ^ (col & 7)) * 8);
        }
        if (swapped) {
#pragma unroll
          for (int i = 0; i < 4; ++i)
#pragma unroll
            for (int j = 0; j < 4; ++j)
              acc[i][j] = __builtin_amdgcn_mfma_f32_16x16x32_bf16(bfr[j], af[i], acc[i][j], 0, 0, 0);
        } else {
#pragma unroll
          for (int i = 0; i < 4; ++i)
#pragma unroll
            for (int j = 0; j < 4; ++j)
              acc[i][j] = __builtin_amdgcn_mfma_f32_16x16x32_bf16(af[i], bfr[j], acc[i][j], 0, 0, 0);
        }
      }
      __syncthreads();
    }
  };

  const int b_ = row0 >> 11;
  const int nb = (row0 & (N_ - 1)) + wm;         // local-n base of this wave
  if (z < 2) {                                   // ---- Q or K (swapped D^T)
    kloop(true);
    const float* bias = (z == 0) ? bq : bk;
    bf16* dst = (z == 0) ? Q : K;
    const float sc = (z == 0) ? (SCALE_ * LOG2E_) : 1.0f;
    // D^T: col(lane&15)=n-side (af), row(g4*4+reg)=feature-side (bfr)
#pragma unroll
    for (int j = 0; j < 4; ++j) {
      const int c = col0 - z * 768 + wn + j * 16 + g4 * 4;  // 4 consecutive feats
      const int h = c / D_, d0 = c % D_;          // 4|48: no head crossing
      const float4 bb = *(const float4*)(bias + c);
      bf16* slabp = dst + (size_t)(b_ * H_ + h) * (N_ * D_);
      const int dpart = (d0 >> 4) * 512 + ((d0 >> 3) & 1) * 256 + (d0 & 7);
#pragma unroll
      for (int i = 0; i < 4; ++i) {
        const int n = nb + i * 16 + mb;
        u32x2 wv;
        wv.x = pk2((acc[i][j][0] + bb.x) * sc, (acc[i][j][1] + bb.y) * sc);
        wv.y = pk2((acc[i][j][2] + bb.z) * sc, (acc[i][j][3] + bb.w) * sc);
        *(u32x2*)(slabp + (n >> 5) * 1536 + dpart + (n & 31) * 8) = wv;
      }
    }
  } else {                                       // ---- V -> Vf (orig order)
    kloop(false);
#pragma unroll
    for (int j = 0; j < 4; ++j) {
      const int oo = col0 - 2 * 768 + wn + j * 16 + mb;
      const int h = oo / D_, d = oo % D_;
      const float bb = bv[oo];
      bf16* slabp = Vf + (size_t)(b_ * H_ + h) * (N_ * 64);
      const int dpart = (d >> 5) * 512 + ((g4 >> 1) * 32 + (d & 31)) * 8 +
                        (g4 & 1) * 4;
#pragma unroll
      for (int i = 0; i < 4; ++i) {
        u32x2 wv;
        wv.x = pk2(acc[i][j][0] + bb, acc[i][j][1] + bb);
        wv.y = pk2(acc[i][j][2] + bb, acc[i][j][3] + bb);
        *(u32x2*)(slabp + ((nb >> 4) + i) * 1024 + dpart) = wv;
      }
    }
  }
}

// ---- Kernel 2: LDS-staged register flash attention, 512-thread blocks.
// 8 waves share ONE staged K/V tile (QBLK=32/wave, 256 q-rows/block):
// per-CU staging + LDS-read traffic halves vs 4-wave blocks, at constant
// 16 waves/CU. bf16 residual from xb; sequential per-wave chain (R5-proven).
__global__ __launch_bounds__(512, 2) void attn_mfma(
    const bf16* __restrict__ Qf, const bf16* __restrict__ Kf,
    const bf16* __restrict__ Vf, const bf16* __restrict__ xb,
    bf16* __restrict__ Yb)
{
  __shared__ __align__(16) bf16 Ls[2 * 7168];    // 2 bufs x (6KB K + 8KB V)

  const int tid  = threadIdx.x;
  const int lane = tid & 63, wid = tid >> 6;     // wid 0..7
  const int m5 = lane & 31, hi = lane >> 5;
  const int bh = blockIdx.x;
  const int b_ = bh >> 4, h = bh & 15;
  const int q0 = blockIdx.y * 256 + wid * 32;    // 256 q rows per block
  const size_t slab  = (size_t)bh * (N_ * D_);
  const size_t slabV = (size_t)bh * (N_ * 64);

  // Q fragments (32 q rows x 48 d), live whole kernel
  bf16x8 qf[3];
  const int kgq = q0 >> 5;
#pragma unroll
  for (int kc = 0; kc < 3; ++kc)
    qf[kc] = *(const bf16x8*)(Qf + slab + (size_t)(((kgq * 3 + kc) * 64) + lane) * 8);

  f32x16 zf;
#pragma unroll
  for (int r = 0; r < 16; ++r) zf[r] = 0.f;

  f32x16 Oacc[2];
#pragma unroll
  for (int dt = 0; dt < 2; ++dt)
#pragma unroll
    for (int r = 0; r < 16; ++r) Oacc[dt][r] = 0.f;

  // stage tile t (64 keys) into buffer buf: chunks 0-5 = K (6KB), 6-13 = V (8KB)
  const bf16* kb = Kf + slab  + (size_t)lane * 8;
  const bf16* vb = Vf + slabV + (size_t)lane * 8;
  auto stage = [&](int t, int buf) {
    bf16* dstb = Ls + buf * 7168;
    const bf16* kt = kb + (size_t)t * 3072;
    const bf16* vt = vb + (size_t)t * 4096;
    for (int c = wid; c < 14; c += 8) {          // 8 waves: <=2 chunks each
      if (c < 6) gload_lds16(kt + c * 512, dstb + c * 512);
      else       gload_lds16(vt + (c - 6) * 512, dstb + c * 512);
    }
  };

  // compute one 32-key sub-tile from LDS buffer buf
  auto sub = [&](int buf, int s) {
    const bf16* Lb = Ls + buf * 7168 + (size_t)lane * 8;
    bf16x8 kf[3], vA[2][2];
#pragma unroll
    for (int kc = 0; kc < 3; ++kc)
      kf[kc] = *(const bf16x8*)(Lb + (s * 3 + kc) * 512);
#pragma unroll
    for (int ks = 0; ks < 2; ++ks)
#pragma unroll
      for (int dt = 0; dt < 2; ++dt)
        vA[ks][dt] = *(const bf16x8*)(Lb + (6 + s * 4 + ks * 2 + dt) * 512);
    f32x16 S;
    __builtin_amdgcn_s_setprio(1);
    S = __builtin_amdgcn_mfma_f32_32x32x16_bf16(kf[0], qf[0], zf, 0, 0, 0);
    S = __builtin_amdgcn_mfma_f32_32x32x16_bf16(kf[1], qf[1], S, 0, 0, 0);
    S = __builtin_amdgcn_mfma_f32_32x32x16_bf16(kf[2], qf[2], S, 0, 0, 0);
    __builtin_amdgcn_s_setprio(0);
#pragma unroll
    for (int r = 0; r < 16; ++r)
      S[r] = __builtin_amdgcn_exp2f(S[r]);
    // S reg 4*qq+rr = P[q=lane&31][k32 = rr + 8*qq + 4*hi]
#pragma unroll
    for (int ks = 0; ks < 2; ++ks) {
      const int qa = ks * 2;
      const unsigned A0 = pk2(S[4 * qa + 0], S[4 * qa + 1]);
      const unsigned A1 = pk2(S[4 * qa + 2], S[4 * qa + 3]);
      const unsigned B0 = pk2(S[4 * qa + 4], S[4 * qa + 5]);
      const unsigned B1 = pk2(S[4 * qa + 6], S[4 * qa + 7]);
      const u32x2 r02 = __builtin_amdgcn_permlane32_swap(A0, B0, false, false);
      const u32x2 r13 = __builtin_amdgcn_permlane32_swap(A1, B1, false, false);
      u32x4 pw;
      pw.x = r02.x; pw.y = r13.x; pw.z = r02.y; pw.w = r13.y;
      const bf16x8 pb = (bf16x8)pw;
      __builtin_amdgcn_s_setprio(1);
      Oacc[0] = __builtin_amdgcn_mfma_f32_32x32x16_bf16(vA[ks][0], pb, Oacc[0], 0, 0, 0);
      Oacc[1] = __builtin_amdgcn_mfma_f32_32x32x16_bf16(vA[ks][1], pb, Oacc[1], 0, 0, 0);
      __builtin_amdgcn_s_setprio(0);
    }
  };

  stage(0, 0);
  __syncthreads();
  int buf = 0;
#pragma unroll 1
  for (int t = 0; t < 32; ++t) {
    if (t + 1 < 32) stage(t + 1, buf ^ 1);     // prefetch next tile first
    sub(buf, 0);
    sub(buf, 1);
    __syncthreads();                           // drains vmcnt: next buf ready
    buf ^= 1;
  }

  // L[q] lives in Oacc[1] row 16 = reg 8 of hi=0 lanes; broadcast to hi=1.
  const float lf = Oacc[1][8];
  const unsigned lu = __builtin_bit_cast(unsigned, lf);
  const u32x2 lsw = __builtin_amdgcn_permlane32_swap(lu, lu, false, false);
  const float Lv = __builtin_bit_cast(float, lsw.x);
  const float inv = 1.f / Lv;

  const int n = q0 + m5;
  const size_t rowoff = ((size_t)(b_ * N_ + n)) * C_ + h * D_;
#pragma unroll
  for (int qq = 0; qq < 4; ++qq) {
    const size_t off = rowoff + 8 * qq + 4 * hi;      // d = 8qq+4hi .. +3
    const u32x2 xv = *(const u32x2*)(xb + off);       // 4 bf16 residuals
    u32x2 wv;
    wv.x = pk2(Oacc[0][4 * qq + 0] * inv + b2f((unsigned short)(xv.x & 0xffff)),
               Oacc[0][4 * qq + 1] * inv + b2f((unsigned short)(xv.x >> 16)));
    wv.y = pk2(Oacc[0][4 * qq + 2] * inv + b2f((unsigned short)(xv.y & 0xffff)),
               Oacc[0][4 * qq + 3] * inv + b2f((unsigned short)(xv.y >> 16)));
    *(u32x2*)(Yb + off) = wv;
  }
#pragma unroll
  for (int qq = 0; qq < 2; ++qq) {
    const size_t off = rowoff + 32 + 8 * qq + 4 * hi; // d = 32+8qq+4hi .. +3
    const u32x2 xv = *(const u32x2*)(xb + off);
    u32x2 wv;
    wv.x = pk2(Oacc[1][4 * qq + 0] * inv + b2f((unsigned short)(xv.x & 0xffff)),
               Oacc[1][4 * qq + 1] * inv + b2f((unsigned short)(xv.x >> 16)));
    wv.y = pk2(Oacc[1][4 * qq + 2] * inv + b2f((unsigned short)(xv.y & 0xffff)),
               Oacc[1][4 * qq + 3] * inv + b2f((unsigned short)(xv.y >> 16)));
    *(u32x2*)(Yb + off) = wv;
  }
}

// ---- Kernel 3: O projection + residuals. 64x128 tile, XCD-swizzled.
// Swapped MFMA: thread owns 4 consecutive o at fixed r -> float4 stores.
// out[r][o] = acc + bo[o] + float(Yb[r][o]) + x[r][o]
__global__ __launch_bounds__(256) void gemm_out(
    const bf16* __restrict__ Yb, const bf16* __restrict__ Bw,
    const float* __restrict__ bo, const float* __restrict__ x,
    float* __restrict__ out)
{
  __shared__ __align__(16) bf16 As[64 * 64];     // 8 KB
  __shared__ __align__(16) bf16 Bs[128 * 64];    // 16 KB

  // XCD-chunked swizzle: nwg=768=8*96 -> per XCD: 16 row-panels x 6 cols.
  const int lid  = blockIdx.x + 6 * blockIdx.y;
  const int nlid = (lid & 7) * 96 + (lid >> 3);
  const int bx = nlid % 6, by = nlid / 6;

  const int tid  = threadIdx.x;
  const int lane = tid & 63, wid = tid >> 6;
  const int wm = (wid >> 1) * 32, wn = (wid & 1) * 64;
  const int row0 = by * 64, col0 = bx * 128;
  const int mb = lane & 15, g4 = lane >> 4;
  const int srow = lane >> 3;
  const int schunk = (lane & 7) ^ (srow & 7);

  f32x4 acc[2][4];
#pragma unroll
  for (int i = 0; i < 2; ++i)
#pragma unroll
    for (int j = 0; j < 4; ++j) acc[i][j] = (f32x4){0.f, 0.f, 0.f, 0.f};

  for (int k0 = 0; k0 < C_; k0 += 64) {
#pragma unroll
    for (int t = 0; t < 2; ++t) {               // A: 64 rows = 4 waves x 16
      const int rt = wid * 16 + t * 8;
      gload_lds16(Yb + (size_t)(row0 + rt + srow) * C_ + k0 + schunk * 8,
                  As + rt * 64);
    }
#pragma unroll
    for (int t = 0; t < 4; ++t) {               // B: 128 rows = 4 waves x 32
      const int rt = wid * 32 + t * 8;
      gload_lds16(Bw + (size_t)(col0 + rt + srow) * C_ + k0 + schunk * 8,
                  Bs + rt * 64);
    }
    __syncthreads();
#pragma unroll
    for (int ks = 0; ks < 2; ++ks) {
      const int kchunk = ks * 4 + g4;
      bf16x8 af[2], bfr[4];
#pragma unroll
      for (int i = 0; i < 2; ++i) {
        const int row = wm + i * 16 + mb;
        af[i] = *(const bf16x8*)(As + row * 64 + (kchunk ^ (row & 7)) * 8);
      }
#pragma unroll
      for (int j = 0; j < 4; ++j) {
        const int col = wn + j * 16 + mb;
        bfr[j] = *(const bf16x8*)(Bs + col * 64 + (kchunk ^ (col & 7)) * 8);
      }
#pragma unroll
      for (int i = 0; i < 2; ++i)
#pragma unroll
        for (int j = 0; j < 4; ++j)
          acc[i][j] = __builtin_amdgcn_mfma_f32_16x16x32_bf16(bfr[j], af[i], acc[i][j], 0, 0, 0);
    }
    __syncthreads();
  }

  // D^T: col(lane&15)=r-side (af rows), row(g4*4+reg)=o-side (bfr rows)
#pragma unroll
  for (int j = 0; j < 4; ++j) {
    const int o0 = col0 + wn + j * 16 + g4 * 4;
    const float4 bb = *(const float4*)(bo + o0);
#pragma unroll
    for (int i = 0; i < 2; ++i) {
      const int r = row0 + wm + i * 16 + mb;
      const size_t off = (size_t)r * C_ + o0;
      const u32x2 yv = *(const u32x2*)(Yb + off);   // 4 bf16
      const float4 xr = *(const float4*)(x + off);
      float4 ov;
      ov.x = acc[i][j][0] + bb.x + b2f((unsigned short)(yv.x & 0xffff)) + xr.x;
      ov.y = acc[i][j][1] + bb.y + b2f((unsigned short)(yv.x >> 16))    + xr.y;
      ov.z = acc[i][j][2] + bb.z + b2f((unsigned short)(yv.y & 0xffff)) + xr.z;
      ov.w = acc[i][j][3] + bb.w + b2f((unsigned short)(yv.y >> 16))    + xr.w;
      *(float4*)(out + off) = ov;
    }
  }
}

extern "C" void kernel_launch(void* const* d_in, const int* in_sizes, int n_in,
                              void* d_out, int out_size, void* d_ws, size_t ws_size,
                              hipStream_t stream)
{
  const float* x  = (const float*)d_in[0];
  const float* wq = (const float*)d_in[1];
  const float* bq = (const float*)d_in[2];
  const float* wk = (const float*)d_in[3];
  const float* bk = (const float*)d_in[4];
  const float* wv = (const float*)d_in[5];
  const float* bv = (const float*)d_in[6];
  const float* wo = (const float*)d_in[7];
  const float* bo = (const float*)d_in[8];
  float* out = (float*)d_out;

  const size_t nEl  = (size_t)B_ * N_ * C_;      // 6,291,456
  const size_t wEl  = (size_t)C_ * C_;           // 589,824
  const size_t vfEl = (size_t)B_ * H_ * N_ * 64; // 8,388,608 (padded V frags)
  bf16* Q     = (bf16*)d_ws;                     // fragment layouts
  bf16* K     = Q + nEl;
  bf16* Vf    = K + nEl;                         // padded V A-fragment layout
  bf16* Yb    = Vf + vfEl;                       // y = attn+x, bf16
  bf16* xb    = Yb + nEl;                        // [8192][768] bf16
  bf16* wqkvb = xb + nEl;                        // [2304][768] bf16 stacked
  bf16* wob   = wqkvb + 3 * wEl;                 // [768][768] bf16

  dim3 gcvt(768, 6);                             // job 5 = Vf pad fill
  cvt_bf16<<<gcvt, dim3(256), 0, stream>>>(x, wq, wk, wv, wo, xb, wqkvb, wob, Vf);

  dim3 gqkv(18, 64);                             // 2304/128 x 8192/128
  gemm_qkv<<<gqkv, dim3(256), 0, stream>>>(xb, wqkvb, bq, bk, bv, Q, K, Vf);

  dim3 gattn(B_ * H_, N_ / 256);                 // (64, 8), 512 thr, QBLK=32
  attn_mfma<<<gattn, dim3(512), 0, stream>>>(Q, K, Vf, xb, Yb);

  dim3 gout(6, 128);                             // 768/128 x 8192/64
  gemm_out<<<gout, dim3(256), 0, stream>>>(Yb, wob, bo, x, out);
}